// Round 14
// baseline (607.591 us; speedup 1.0000x reference)
//
#include <hip/hip_runtime.h>
#include <math.h>

// ---------------------------------------------------------------------------
// AdvancedMixConsole: 64 tracks x 131072 samples.
//   gain -> 6 biquads (chunk-parallel linear recurrence, 12-dim state)
//        -> compressor: parallel static gain; serial smoother over
//           WINDOW MAPS (max-affine); window maps tree-composed W=64->128
//        -> pan/mix (parallel, two-stage).
// R25 = R24 with the k_compose slope-staging off-by-one fixed: `if(l<=64)`
//      on a 64-lane block never stages SL[64] (aa^64) -> every composed
//      term with k=64 used uninitialized LDS (absmax 203). Now staged with
//      a strided loop (lane 0 carries index 64). All else identical:
//      (max,+)-convolve adjacent 64-window maps into 128-window maps,
//      smoother 1024 steps (2 slopes/lane + uniform), mix1 SMW=128.
// ---------------------------------------------------------------------------

#define S_LEN 131072
#define NTR   64
#define CCH   512          // chunks (biquad phase)
#define LCH   256          // samples per chunk
#define GRP   32           // level-2 scan groups
#define GCH   16           // chunks per group
#define SMW   128          // smoother window (after compose)
#define NWIN  1024         // composed windows per track
#define NST3  2048         // original 64-sample windows per track
#define WPC3  4            // windows per biquad chunk (LCH/SMW0)
#define RECF  68           // floats per original record
#define REC2  136          // floats per composed record (129 used)
#define SCH   64           // k_smooth steps per LDS chunk
#define NCH   16           // LDS chunks (1024/64)
#define CHF4  2176         // float4s per chunk (64*136/4 = 128*68/4)

typedef float v2f __attribute__((ext_vector_type(2)));

// ws offsets in floats (total ~73.3 MB)
#define OFF_Y    0ull              // [131072][64]      EQ output y, sample-major
#define OFF_CI   8388608ull        // [64][2048][68]    intercept records; composed in-place to [64][1024][136]
#define OFF_TV   8388608ull        // [131072][64]      tv (ALIASES CI; used after k_smooth)
#define OFF_QB   17302528ull       // [64][2048]        boundary q per composed window (1024 used)
#define OFF_W    17433600ull       // [64][2]           cos/sin pan weights
#define OFF_COEF 17433728ull       // [64][32]          biquad coeffs
#define OFF_COMP 17435776ull       // [64][128]         compressor consts + 65 W=64 slopes
#define OFF_A    17443968ull       // [64][144]         cascade transition matrix
#define OFF_M    17453184ull       // [64][144]         A^LCH
#define OFF_F    17462400ull       // [CCH][12][64]     zero-init chunk finals (track-minor)
#define OFF_Z    17855616ull       // [CCH][12][64]     chunk init states (track-minor)
#define OFF_GF   18248832ull       // [32][12][64]      group from-zero finals
#define OFF_GZ   18273408ull       // [32][12][64]      group initial states
#define OFF_M2   18297984ull       // [64][144]         (A^LCH)^16
#define OFF_CMP2 18307200ull       // [64][136]         129 W=128 slopes aa^j ar^(128-j)

// ---------------------------------------------------------------------------
__global__ __launch_bounds__(64) void k_setup(const float* __restrict__ mp,
                                              float* __restrict__ ws) {
  int n = threadIdx.x;
  if (n >= NTR) return;
  const float* p = mp + n * 26;
  auto dn = [&](int i, double lo, double hi) { return (double)p[i] * (hi - lo) + lo; };

  double gain_db = dn(0, -24.0, 24.0);
  double glin = pow(10.0, gain_db / 20.0);
  const double nyq = 21050.0;  // 44100//2 - 1000

  double fg[6] = {dn(1,-24,24), dn(4,-24,24), dn(7,-24,24), dn(10,-24,24), dn(13,-24,24), dn(16,-24,24)};
  double ff[6] = {dn(2,20,2000), dn(5,80,2000), dn(8,2000,8000), dn(11,8000,12000), dn(14,12000,nyq), dn(17,6000,nyq)};
  double fq[6] = {dn(3,0.1,5), dn(6,0.1,5), dn(9,0.1,5), dn(12,0.1,5), dn(15,0.1,5), dn(18,0.1,5)};

  double B0[6], B1[6], B2[6], A1[6], A2[6];
  for (int k = 0; k < 6; k++) {
    double A  = pow(10.0, fg[k] / 40.0);
    double w0 = 2.0 * M_PI * ff[k] / 44100.0;
    double cw = cos(w0), sw = sin(w0);
    double al = sw / (2.0 * fq[k]);
    double sA = sqrt(A);
    double b0, b1, b2, a0, a1, a2;
    if (k == 0) {           // low shelf
      b0 = A*((A+1)-(A-1)*cw + 2*sA*al);
      b1 = 2*A*((A-1)-(A+1)*cw);
      b2 = A*((A+1)-(A-1)*cw - 2*sA*al);
      a0 = (A+1)+(A-1)*cw + 2*sA*al;
      a1 = -2*((A-1)+(A+1)*cw);
      a2 = (A+1)+(A-1)*cw - 2*sA*al;
    } else if (k == 5) {    // high shelf
      b0 = A*((A+1)+(A-1)*cw + 2*sA*al);
      b1 = -2*A*((A-1)+(A+1)*cw);
      b2 = A*((A+1)+(A-1)*cw - 2*sA*al);
      a0 = (A+1)-(A-1)*cw + 2*sA*al;
      a1 = 2*((A-1)-(A+1)*cw);
      a2 = (A+1)-(A-1)*cw - 2*sA*al;
    } else {                // peak
      b0 = 1 + al*A; b1 = -2*cw; b2 = 1 - al*A;
      a0 = 1 + al/A; a1 = -2*cw; a2 = 1 - al/A;
    }
    B0[k] = b0/a0; B1[k] = b1/a0; B2[k] = b2/a0; A1[k] = a1/a0; A2[k] = a2/a0;
  }
  // fold input gain into stage-0 numerator
  B0[0] *= glin; B1[0] *= glin; B2[0] *= glin;

  float* cf = ws + OFF_COEF + n * 32;
  for (int k = 0; k < 6; k++) {
    cf[k*5+0] = (float)B0[k]; cf[k*5+1] = (float)B1[k]; cf[k*5+2] = (float)B2[k];
    cf[k*5+3] = (float)A1[k]; cf[k*5+4] = (float)A2[k];
  }

  // compressor + pan constants
  double T = dn(19,-60,0), R = dn(20,1,10), atk = dn(21,1,1000), rel = dn(22,1,1000);
  double Kn = dn(23,3,24), mk = dn(24,0,24);
  double a_a = exp(-1.0 / (44100.0 * atk * 0.001));
  double a_r = exp(-1.0 / (44100.0 * rel * 0.001));
  double s   = (a_a < a_r) ? 1.0 : -1.0;     // q = s*p makes the recurrence pure-max
  double kca = s * (1.0 - a_a), kcr = s * (1.0 - a_r);
  double invR = 1.0 / R;
  const double K10 = 0.16609640474436813;    // log2(10)/20
  double theta = (double)p[25] * (M_PI / 2.0);

  float* cm = ws + OFF_COMP + n * 128;
  cm[0] = (float)a_a;  cm[1] = (float)a_r;  cm[2] = (float)kca; cm[3] = (float)kcr;
  cm[4] = (float)T;    cm[5] = (float)(Kn * 0.5);
  cm[6] = (float)(1.0 - invR);
  cm[7] = (float)((1.0 - invR) / (2.0 * Kn));
  cm[8] = (float)(mk * K10);   cm[9] = (float)(s * K10);
  cm[10] = (float)cos(theta);  cm[11] = (float)sin(theta);
  // 65 W=64 slopes aa^j ar^(64-j) — incremental (2 pow + 64 fmul)
  {
    double sj = pow(a_r, 64.0);
    double ratio = a_a / a_r;
    for (int j = 0; j <= 64; j++) { cm[16+j] = (float)sj; sj *= ratio; }
  }
  // 129 W=128 slopes aa^j ar^(128-j)
  {
    float* c2t = ws + OFF_CMP2 + (size_t)n*REC2;
    double sj = pow(a_r, 128.0);
    double ratio = a_a / a_r;
    for (int j = 0; j <= 128; j++) { c2t[j] = (float)sj; sj *= ratio; }
  }

  float* wp = ws + OFF_W + n*2;
  wp[0] = (float)cos(theta); wp[1] = (float)sin(theta);

  // homogeneous (x=0) cascade transition matrix, state = [s1_1,s2_1,...,s1_6,s2_6]
  double Am[12][12], yv[12], ny[12];
  for (int r = 0; r < 12; r++) { yv[r] = 0; for (int c = 0; c < 12; c++) Am[r][c] = 0; }
  for (int k = 0; k < 6; k++) {
    for (int c = 0; c < 12; c++) ny[c] = B0[k] * yv[c];
    ny[2*k] += 1.0;                                  // y_k = b0*y_{k-1} + s1_k
    for (int c = 0; c < 12; c++) Am[2*k][c]   = B1[k]*yv[c] - A1[k]*ny[c];
    Am[2*k][2*k+1] += 1.0;                           // + s2_k
    for (int c = 0; c < 12; c++) Am[2*k+1][c] = B2[k]*yv[c] - A2[k]*ny[c];
    for (int c = 0; c < 12; c++) yv[c] = ny[c];
  }
  float* Aw = ws + OFF_A + n * 144;
  for (int r = 0; r < 12; r++)
    for (int c = 0; c < 12; c++) Aw[r*12+c] = (float)Am[r][c];
}

// ---------------------------------------------------------------------------
// 12 squarings: store A^256 (=A^LCH) after 8, A^4096 (=(A^LCH)^16) after 12.
__global__ __launch_bounds__(192) void k_matpow(float* __restrict__ ws) {
  __shared__ float As[144];
  int n = blockIdx.x, t = threadIdx.x;
  int r = t / 12, c = t % 12;
  if (t < 144) As[t] = ws[OFF_A + (size_t)n*144 + t];
  __syncthreads();
  for (int it = 0; it < 12; ++it) {
    float acc = 0.f;
    if (t < 144) {
      #pragma unroll
      for (int k = 0; k < 12; k++) acc += As[r*12+k] * As[k*12+c];
    }
    __syncthreads();
    if (t < 144) As[t] = acc;
    __syncthreads();
    if (it == 7 && t < 144) ws[OFF_M + (size_t)n*144 + t] = As[t];   // A^256
  }
  if (t < 144) ws[OFF_M2 + (size_t)n*144 + t] = As[t];               // A^4096
}

// ---------------------------------------------------------------------------
__device__ __forceinline__ void load_coefs(const float* cf, float* b0, v2f* bb, v2f* naa) {
  #pragma unroll
  for (int k = 0; k < 6; k++) {
    b0[k]  = cf[k*5+0];
    bb[k]  = (v2f){cf[k*5+1], cf[k*5+2]};
    naa[k] = (v2f){-cf[k*5+3], -cf[k*5+4]};
  }
}

__device__ __forceinline__ float cascade_step(float x, float* b0, v2f* bb, v2f* naa, v2f* st) {
  #pragma unroll
  for (int k = 0; k < 6; k++) {
    float y  = fmaf(b0[k], x, st[k].x);
    v2f upd  = __builtin_elementwise_fma(bb[k], (v2f){x, x}, (v2f){st[k].y, 0.f});
    st[k]    = __builtin_elementwise_fma(naa[k], (v2f){y, y}, upd);
    x = y;
  }
  return x;
}

// phase 1: zero-init chunk finals
__global__ __launch_bounds__(64) void k_phase1(const float* __restrict__ tracks,
                                               float* __restrict__ ws) {
  int j = blockIdx.x, n = threadIdx.x;
  float b0[6]; v2f bb[6], naa[6];
  load_coefs(ws + OFF_COEF + n*32, b0, bb, naa);
  v2f st[6];
  #pragma unroll
  for (int k = 0; k < 6; k++) st[k] = (v2f){0.f, 0.f};
  const float4* xp = (const float4*)(tracks + (size_t)n*S_LEN + (size_t)j*LCH);
  for (int i4 = 0; i4 < LCH/4; ++i4) {
    float4 xq = xp[i4];
    float xs[4] = {xq.x, xq.y, xq.z, xq.w};
    #pragma unroll
    for (int u = 0; u < 4; u++) (void)cascade_step(xs[u], b0, bb, naa, st);
  }
  // track-minor layout [j][r][64]: 12 coalesced scalar stores
  float* f = ws + OFF_F + (size_t)j*(12*NTR) + n;
  #pragma unroll
  for (int k = 0; k < 6; k++) { f[(2*k)*64] = st[k].x; f[(2*k+1)*64] = st[k].y; }
}

// ---------------------------------------------------------------------------
// Blocked scan machinery (R21). Quad structure: 4 lanes per track instance.
__device__ __forceinline__ float qperm(float x, const int sel) {
  int xi = __float_as_int(x);
  int yi;
  switch (sel) {   // lane j receives from lane (j+k)&3 within its quad
    case 1:  yi = __builtin_amdgcn_update_dpp(xi, xi, 0x39, 0xf, 0xf, false); break; // [1,2,3,0]
    case 2:  yi = __builtin_amdgcn_update_dpp(xi, xi, 0x4E, 0xf, 0xf, false); break; // [2,3,0,1]
    default: yi = __builtin_amdgcn_update_dpp(xi, xi, 0x93, 0xf, 0xf, false); break; // [3,0,1,2]
  }
  return __int_as_float(yi);
}

// 36 named M scalars, columns in quad-rotation order (rows 3*sub..3*sub+2).
#define M_DECL(MBASE)                                                         \
  const int c0 = 3*((sub + 0) & 3), c1 = 3*((sub + 1) & 3),                   \
            c2 = 3*((sub + 2) & 3), c3 = 3*((sub + 3) & 3);                   \
  const float* Mb = (MBASE) + (3*sub)*12;                                     \
  float m0_0_0 = Mb[0*12+c0+0], m0_0_1 = Mb[1*12+c0+0], m0_0_2 = Mb[2*12+c0+0];\
  float m0_1_0 = Mb[0*12+c0+1], m0_1_1 = Mb[1*12+c0+1], m0_1_2 = Mb[2*12+c0+1];\
  float m0_2_0 = Mb[0*12+c0+2], m0_2_1 = Mb[1*12+c0+2], m0_2_2 = Mb[2*12+c0+2];\
  float m1_0_0 = Mb[0*12+c1+0], m1_0_1 = Mb[1*12+c1+0], m1_0_2 = Mb[2*12+c1+0];\
  float m1_1_0 = Mb[0*12+c1+1], m1_1_1 = Mb[1*12+c1+1], m1_1_2 = Mb[2*12+c1+1];\
  float m1_2_0 = Mb[0*12+c1+2], m1_2_1 = Mb[1*12+c1+2], m1_2_2 = Mb[2*12+c1+2];\
  float m2_0_0 = Mb[0*12+c2+0], m2_0_1 = Mb[1*12+c2+0], m2_0_2 = Mb[2*12+c2+0];\
  float m2_1_0 = Mb[0*12+c2+1], m2_1_1 = Mb[1*12+c2+1], m2_1_2 = Mb[2*12+c2+1];\
  float m2_2_0 = Mb[0*12+c2+2], m2_2_1 = Mb[1*12+c2+2], m2_2_2 = Mb[2*12+c2+2];\
  float m3_0_0 = Mb[0*12+c3+0], m3_0_1 = Mb[1*12+c3+0], m3_0_2 = Mb[2*12+c3+0];\
  float m3_1_0 = Mb[0*12+c3+1], m3_1_1 = Mb[1*12+c3+1], m3_1_2 = Mb[2*12+c3+1];\
  float m3_2_0 = Mb[0*12+c3+2], m3_2_1 = Mb[1*12+c3+2], m3_2_2 = Mb[2*12+c3+2];

// one scan step: z = M z + f, f at (FP)[0],[64],[128]
#define SCAN_STEP(FP)                                                         \
  {                                                                           \
    float t10 = qperm(z0,1), t11 = qperm(z1,1), t12 = qperm(z2,1);            \
    float t20 = qperm(z0,2), t21 = qperm(z1,2), t22 = qperm(z2,2);            \
    float t30 = qperm(z0,3), t31 = qperm(z1,3), t32 = qperm(z2,3);            \
    float a0 = (FP)[0], a1 = (FP)[64], a2 = (FP)[128];                        \
    a0 = fmaf(m0_0_0, z0, a0);  a1 = fmaf(m0_0_1, z0, a1);  a2 = fmaf(m0_0_2, z0, a2);  \
    a0 = fmaf(m0_1_0, z1, a0);  a1 = fmaf(m0_1_1, z1, a1);  a2 = fmaf(m0_1_2, z1, a2);  \
    a0 = fmaf(m0_2_0, z2, a0);  a1 = fmaf(m0_2_1, z2, a1);  a2 = fmaf(m0_2_2, z2, a2);  \
    a0 = fmaf(m1_0_0, t10, a0); a1 = fmaf(m1_0_1, t10, a1); a2 = fmaf(m1_0_2, t10, a2); \
    a0 = fmaf(m1_1_0, t11, a0); a1 = fmaf(m1_1_1, t11, a1); a2 = fmaf(m1_1_2, t11, a2); \
    a0 = fmaf(m1_2_0, t12, a0); a1 = fmaf(m1_2_1, t12, a1); a2 = fmaf(m1_2_2, t12, a2); \
    a0 = fmaf(m2_0_0, t20, a0); a1 = fmaf(m2_0_1, t20, a1); a2 = fmaf(m2_0_2, t20, a2); \
    a0 = fmaf(m2_1_0, t21, a0); a1 = fmaf(m2_1_1, t21, a1); a2 = fmaf(m2_1_2, t21, a2); \
    a0 = fmaf(m2_2_0, t22, a0); a1 = fmaf(m2_2_1, t22, a1); a2 = fmaf(m2_2_2, t22, a2); \
    a0 = fmaf(m3_0_0, t30, a0); a1 = fmaf(m3_0_1, t30, a1); a2 = fmaf(m3_0_2, t30, a2); \
    a0 = fmaf(m3_1_0, t31, a0); a1 = fmaf(m3_1_1, t31, a1); a2 = fmaf(m3_1_2, t31, a2); \
    a0 = fmaf(m3_2_0, t32, a0); a1 = fmaf(m3_2_1, t32, a1); a2 = fmaf(m3_2_2, t32, a2); \
    z0 = a0; z1 = a1; z2 = a2;                                                \
  }

// level-1: per-group from-zero finals (4-wave TLP hides reloads).
__global__ __launch_bounds__(256, 1) void k_scanz_a(float* __restrict__ ws) {
  const int tid = threadIdx.x;
  const int sub = tid & 3;
  const int n   = tid >> 2;          // track 0..63
  const int g   = blockIdx.x;        // group 0..31
  M_DECL(ws + OFF_M + (size_t)n*144)
  float z0 = 0.f, z1 = 0.f, z2 = 0.f;
  const float* __restrict__ fb = ws + OFF_F + (size_t)(g*GCH)*768 + (3*sub)*64 + n;
  #pragma unroll 4
  for (int k = 0; k < GCH; ++k) SCAN_STEP(fb + (size_t)k*768)
  float* gf = ws + OFF_GF + (size_t)g*768 + (3*sub)*64 + n;
  gf[0] = z0; gf[64] = z1; gf[128] = z2;
}

// level-2: serial scan over 32 group boundaries with M16=(A^LCH)^16.
__global__ __launch_bounds__(64, 1) void k_scanz_b(float* __restrict__ ws) {
  const int l   = threadIdx.x;
  const int sub = l & 3;
  const int n   = blockIdx.x*16 + (l >> 2);
  M_DECL(ws + OFF_M2 + (size_t)n*144)
  float z0 = 0.f, z1 = 0.f, z2 = 0.f;
  const float* __restrict__ fb = ws + OFF_GF + (3*sub)*64 + n;
  float*       __restrict__  zb = ws + OFF_GZ + (3*sub)*64 + n;
  for (int G = 0; G < GRP; ++G) {
    float* zp = zb + (size_t)G*768;
    zp[0] = z0; zp[64] = z1; zp[128] = z2;
    SCAN_STEP(fb + (size_t)G*768)
  }
}

// level-3: re-scan each group from its correct initial state.
__global__ __launch_bounds__(256, 1) void k_scanz_c(float* __restrict__ ws) {
  const int tid = threadIdx.x;
  const int sub = tid & 3;
  const int n   = tid >> 2;
  const int g   = blockIdx.x;
  M_DECL(ws + OFF_M + (size_t)n*144)
  const float* gz = ws + OFF_GZ + (size_t)g*768 + (3*sub)*64 + n;
  float z0 = gz[0], z1 = gz[64], z2 = gz[128];
  const float* __restrict__ fb = ws + OFF_F + (size_t)(g*GCH)*768 + (3*sub)*64 + n;
  float*       __restrict__  zb = ws + OFF_Z + (size_t)(g*GCH)*768 + (3*sub)*64 + n;
  #pragma unroll 4
  for (int k = 0; k < GCH; ++k) {
    float* zp = zb + (size_t)k*768;
    zp[0] = z0; zp[64] = z1; zp[128] = z2;
    SCAN_STEP(fb + (size_t)k*768)
  }
}

// phase 3: correct-init EQ; per-sample static gain; per-64-sample-window
// composed max-affine intercepts I[0..64]; 272B records [track][step][68].
__global__ __launch_bounds__(64, 1) void k_phase3(const float* __restrict__ tracks,
                                                  float* __restrict__ ws) {
  int j = blockIdx.x, n = threadIdx.x;
  float b0[6]; v2f bb[6], naa[6];
  load_coefs(ws + OFF_COEF + n*32, b0, bb, naa);
  const float* cm = ws + OFF_COMP + n*128;
  float a_a = cm[0], a_r = cm[1], kca = cm[2], kcr = cm[3];
  float T = cm[4], hK = cm[5], cg1 = cm[6], cg2 = cm[7];
  v2f st[6];
  const float* zp = ws + OFF_Z + (size_t)j*(12*NTR) + n;   // track-minor: 12 coalesced loads
  #pragma unroll
  for (int k = 0; k < 6; k++) st[k] = (v2f){zp[(2*k)*64], zp[(2*k+1)*64]};

  const float4* xp = (const float4*)(tracks + (size_t)n*S_LEN + (size_t)j*LCH);
  float* yb = ws + OFF_Y + (size_t)j*LCH*64 + n;                        // [sample][track]
  float* cw = ws + OFF_CI + (size_t)n*(NST3*RECF) + (size_t)j*WPC3*RECF;

  for (int w = 0; w < WPC3; ++w) {
    float I[65];
    I[0] = 0.f;
    #pragma unroll
    for (int jj = 1; jj < 65; ++jj) I[jj] = -1e30f;
    #pragma unroll
    for (int i4 = 0; i4 < 16; ++i4) {
      float4 xq = xp[w*16 + i4];
      float xs[4] = {xq.x, xq.y, xq.z, xq.w};
      #pragma unroll
      for (int u = 0; u < 4; ++u) {
        const int i = i4*4 + u;
        float y = cascade_step(xs[u], b0, bb, naa, st);
        yb[(w*64 + i)*64] = y;
        float v   = fabsf(y) + 1e-8f;
        float xdb = 6.020599913279624f * __log2f(v);
        float d   = xdb - T;
        float dk  = d + hK;
        float gg  = (d > hK) ? (cg1*d) : (cg2*dk*dk);
        gg = (d < -hK) ? 0.f : gg;
        float ca = kca*gg, cr = kcr*gg;
        // compose one sample into the window map (descending j, in place)
        #pragma unroll
        for (int jj = 64; jj >= 0; --jj) {
          if (jj <= i+1) {
            float up = (jj > 0) ? fmaf(a_a, I[jj-1], ca) : -1e30f;
            I[jj] = fmaxf(up, fmaf(a_r, I[jj], cr));
          }
        }
      }
    }
    float4* cq = (float4*)(cw + (size_t)w*RECF);
    #pragma unroll
    for (int r = 0; r < 16; ++r)
      cq[r] = make_float4(I[4*r], I[4*r+1], I[4*r+2], I[4*r+3]);
    (cw + (size_t)w*RECF)[64] = I[64];
    (cw + (size_t)w*RECF)[65] = -1e30f;
    (cw + (size_t)w*RECF)[66] = -1e30f;
    (cw + (size_t)w*RECF)[67] = -1e30f;
  }
}

// ---------------------------------------------------------------------------
// (max,+) window composition: pairs of 64-window maps -> 128-window maps.
// Block = 64 lanes = 64 pairs of one track segment; 128 input records staged
// TRANSPOSED in LDS ([off][128] -> per-(m,k) reads are 2-way-conflict-free);
// output written IN-PLACE over the block's own input span at stride 136.
// Out[m] = max_{k} SL[k]*IE[m-k] + IL[k],  k in [max(0,m-64), min(64,m)].
__global__ __launch_bounds__(64, 1) void k_compose(float* __restrict__ ws) {
  __shared__ float L[RECF*128 + 72];     // 8704 transposed floats + 65 slopes
  const int l   = threadIdx.x;
  const int n   = blockIdx.x >> 4;       // track
  const int seg = blockIdx.x & 15;       // 64-pair segment
  float* gbase = ws + OFF_CI + (size_t)n*(NST3*RECF) + (size_t)seg*(128*RECF);

  // stage 128 records, transposed: record r float f -> L[f*128 + r]
  for (int i = l; i < 128*RECF/4; i += 64) {
    float4 v = ((const float4*)gbase)[i];
    int r = i / 17;                      // 17 float4 per 68-float record
    int f = (i % 17) * 4;
    L[(f+0)*128 + r] = v.x;
    L[(f+1)*128 + r] = v.y;
    L[(f+2)*128 + r] = v.z;
    L[(f+3)*128 + r] = v.w;
  }
  // 65 slopes: strided so index 64 is staged too (R24 bug: if(l<=64) with
  // 64 lanes never staged SL[64] -> garbage in every k=64 term).
  for (int i = l; i <= 64; i += 64)
    L[RECF*128 + i] = ws[OFF_COMP + (size_t)n*128 + 16 + i];
  __syncthreads();

  const int rE = 2*l, rL = 2*l + 1;      // early/late record columns
  float* gout = gbase + (size_t)l*REC2;  // pair l -> in-place record
  const float* SL = &L[RECF*128];
  for (int m = 0; m <= 128; ++m) {
    const int kmin = (m > 64) ? (m - 64) : 0;
    const int kmax = (m < 64) ? m : 64;
    float acc = -1e30f;
    for (int k = kmin; k <= kmax; ++k)
      acc = fmaxf(acc, fmaf(SL[k], L[(m-k)*128 + rE], L[k*128 + rL]));
    gout[m] = acc;
  }
}

// ---------------------------------------------------------------------------
// serial max-affine smoother over COMPOSED W=128 maps. 1024 steps/track.
// Lane l owns slopes 2l,2l+1 (regs) + uniform term 128. Per step:
// ds_read_b64 + uniform read, 3 fma, max3, 6-stage fused DPP reduce,
// readlane -> SGPR q. 8-step A/B banks amortize lgkmcnt. Producer waves
// 1-3 double-buffer 64-record (34.8KB) chunks.
#define KSTEP2(IV, UV, SS)                                                    \
  {                                                                           \
    float f0  = fmaf(Sv0, qs, (IV).x);                                        \
    float f1  = fmaf(Sv1, qs, (IV).y);                                        \
    float fu  = fmaf(S128v, qs, (UV));                                        \
    float t   = fmaxf(fmaxf(f0, f1), fu);                                     \
    asm("s_nop 1\n\t"                                                         \
        "v_max_f32_dpp %0, %0, %0 row_shr:1 row_mask:0xf bank_mask:0xf\n\t"   \
        "s_nop 1\n\t"                                                         \
        "v_max_f32_dpp %0, %0, %0 row_shr:2 row_mask:0xf bank_mask:0xf\n\t"   \
        "s_nop 1\n\t"                                                         \
        "v_max_f32_dpp %0, %0, %0 row_shr:4 row_mask:0xf bank_mask:0xf\n\t"   \
        "s_nop 1\n\t"                                                         \
        "v_max_f32_dpp %0, %0, %0 row_shr:8 row_mask:0xf bank_mask:0xf\n\t"   \
        "s_nop 1\n\t"                                                         \
        "v_max_f32_dpp %0, %0, %0 row_bcast:15 row_mask:0xa bank_mask:0xf\n\t"\
        "s_nop 1\n\t"                                                         \
        "v_max_f32_dpp %0, %0, %0 row_bcast:31 row_mask:0xc bank_mask:0xf\n\t"\
        "s_nop 1"                                                             \
        : "+v"(t));                                                           \
    qs = __int_as_float(__builtin_amdgcn_readlane(__float_as_int(t), 63));    \
    qsave = ((SS) == l) ? qs : qsave;                                         \
  }

#define LD8B(B, S)                                                            \
  i##B##0 = *(const float2*)(Lb + ((S)+0)*REC2 + 2*l); u##B##0 = Lb[((S)+0)*REC2 + 128]; \
  i##B##1 = *(const float2*)(Lb + ((S)+1)*REC2 + 2*l); u##B##1 = Lb[((S)+1)*REC2 + 128]; \
  i##B##2 = *(const float2*)(Lb + ((S)+2)*REC2 + 2*l); u##B##2 = Lb[((S)+2)*REC2 + 128]; \
  i##B##3 = *(const float2*)(Lb + ((S)+3)*REC2 + 2*l); u##B##3 = Lb[((S)+3)*REC2 + 128]; \
  i##B##4 = *(const float2*)(Lb + ((S)+4)*REC2 + 2*l); u##B##4 = Lb[((S)+4)*REC2 + 128]; \
  i##B##5 = *(const float2*)(Lb + ((S)+5)*REC2 + 2*l); u##B##5 = Lb[((S)+5)*REC2 + 128]; \
  i##B##6 = *(const float2*)(Lb + ((S)+6)*REC2 + 2*l); u##B##6 = Lb[((S)+6)*REC2 + 128]; \
  i##B##7 = *(const float2*)(Lb + ((S)+7)*REC2 + 2*l); u##B##7 = Lb[((S)+7)*REC2 + 128];

#define KS8B(B, S)                                                            \
  KSTEP2(i##B##0, u##B##0, (S)+0)  KSTEP2(i##B##1, u##B##1, (S)+1)            \
  KSTEP2(i##B##2, u##B##2, (S)+2)  KSTEP2(i##B##3, u##B##3, (S)+3)            \
  KSTEP2(i##B##4, u##B##4, (S)+4)  KSTEP2(i##B##5, u##B##5, (S)+5)            \
  KSTEP2(i##B##6, u##B##6, (S)+6)  KSTEP2(i##B##7, u##B##7, (S)+7)

__global__ __launch_bounds__(256, 1) void k_smooth(float* __restrict__ ws) {
  __shared__ float buf[2][SCH*REC2];        // 2 x 34816 B
  const int n = blockIdx.x;
  const int tid = threadIdx.x;
  const int wave = tid >> 6, l = tid & 63;
  const float4* __restrict__ base4 =
      (const float4*)(ws + OFF_CI) + (size_t)n*(NST3*RECF/4);

  // preload chunk 0 (all threads)
  {
    const float4* s4 = base4;
    float4* d4 = (float4*)&buf[0][0];
    for (int i = tid; i < CHF4; i += 256) d4[i] = s4[i];
  }
  __syncthreads();

  const float* c2p = ws + OFF_CMP2 + (size_t)n*REC2;
  const float Sv0   = c2p[2*l];
  const float Sv1   = c2p[2*l + 1];
  const float S128v = c2p[128];
  float qs = 0.f;
  float* qt = ws + OFF_QB + (size_t)n * NST3;
  if (wave == 0) __builtin_amdgcn_s_setprio(3);   // critical serial wave

  for (int c2 = 0; c2 < NCH; ++c2) {
    if (wave != 0) {
      if (c2 + 1 < NCH) {
        const float4* src = base4 + (size_t)(c2+1)*CHF4;
        float4* dst = (float4*)&buf[(c2+1) & 1][0];
        const int p = tid - 64;               // 0..191
        #pragma unroll
        for (int r = 0; r < 3; ++r) {
          int i0 = p + r*768;
          float4 a = src[i0];                 // loads unguarded (global pad)
          float4 b = src[i0 + 192];
          float4 cc = src[i0 + 384];
          float4 d = src[i0 + 576];
          if (i0       < CHF4) dst[i0]       = a;
          if (i0 + 192 < CHF4) dst[i0 + 192] = b;
          if (i0 + 384 < CHF4) dst[i0 + 384] = cc;
          if (i0 + 576 < CHF4) dst[i0 + 576] = d;
        }
      }
    } else {
      const float* Lb = &buf[c2 & 1][0];
      float qsave = 0.f;
      float2 iA0,iA1,iA2,iA3,iA4,iA5,iA6,iA7;
      float  uA0,uA1,uA2,uA3,uA4,uA5,uA6,uA7;
      float2 iB0,iB1,iB2,iB3,iB4,iB5,iB6,iB7;
      float  uB0,uB1,uB2,uB3,uB4,uB5,uB6,uB7;
      LD8B(A, 0)                               // steps 0..7
      for (int s = 0; s < SCH; s += 16) {
        LD8B(B, s+8)                           // steps s+8..s+15
        KS8B(A, s)                             // steps s..s+7
        if (s + 16 < SCH) { LD8B(A, s+16) }    // steps s+16..s+23
        KS8B(B, s+8)                           // steps s+8..s+15
      }
      qt[c2*SCH + l] = qsave;                  // lane l kept step l of chunk
    }
    __syncthreads();
  }
}

// tv = y * 10^((mk - p)/20): exact 128-step reconstruction from boundary q.
// lanes = tracks -> fully coalesced y/tv rows.
__global__ __launch_bounds__(256) void k_mix1(float* __restrict__ ws) {
  const int n  = threadIdx.x & 63;
  const int kk = blockIdx.x*4 + (threadIdx.x >> 6);
  const float* cm = ws + OFF_COMP + n*128;
  const float aa = cm[0], ar = cm[1], kca = cm[2], kcr = cm[3];
  const float T = cm[4], hK = cm[5], cg1 = cm[6], cg2 = cm[7];
  const float mkK = cm[8], sK = cm[9];
  const float* __restrict__ yb  = ws + OFF_Y;
  float* __restrict__       tvb = ws + OFF_TV;
  float q = (kk > 0) ? ws[OFF_QB + (size_t)n*NST3 + (kk-1)] : 0.f;
  #pragma unroll 8
  for (int i = 0; i < SMW; ++i) {
    float y = yb[(size_t)(kk*SMW + i)*64 + n];
    float v   = fabsf(y) + 1e-8f;
    float xdb = 6.020599913279624f * __log2f(v);
    float d   = xdb - T;
    float dk  = d + hK;
    float gg  = (d > hK) ? (cg1*d) : (cg2*dk*dk);
    gg = (d < -hK) ? 0.f : gg;
    q = fmaxf(fmaf(aa, q, kca*gg), fmaf(ar, q, kcr*gg));
    float sc = exp2f(fmaf(-sK, q, mkK));
    tvb[(size_t)(kk*SMW + i)*64 + n] = y * sc;
  }
}

// 16-track pan reduction -> out[b][2][S]
__global__ __launch_bounds__(256) void k_mix2(const float* __restrict__ ws,
                                              float* __restrict__ out) {
  const int b = threadIdx.x & 3;
  const int s = blockIdx.x*64 + (threadIdx.x >> 2);
  const float* __restrict__ tvb = ws + OFF_TV;
  const float2* __restrict__ wp = (const float2*)(ws + OFF_W);
  float accL = 0.f, accR = 0.f;
  const int n0 = b*16;
  #pragma unroll
  for (int t = 0; t < 16; ++t) {
    float tv = tvb[(size_t)s*64 + n0 + t];
    float2 w2 = wp[n0 + t];
    accL = fmaf(w2.x, tv, accL);
    accR = fmaf(w2.y, tv, accR);
  }
  out[(size_t)(b*2 + 0)*S_LEN + s] = accL;
  out[(size_t)(b*2 + 1)*S_LEN + s] = accR;
}

// ---------------------------------------------------------------------------
extern "C" void kernel_launch(void* const* d_in, const int* in_sizes, int n_in,
                              void* d_out, int out_size, void* d_ws, size_t ws_size,
                              hipStream_t stream) {
  const float* tracks = (const float*)d_in[0];
  const float* mp     = (const float*)d_in[1];
  float* ws  = (float*)d_ws;
  float* out = (float*)d_out;

  hipLaunchKernelGGL(k_setup,   dim3(1),    dim3(64),  0, stream, mp, ws);
  hipLaunchKernelGGL(k_matpow,  dim3(64),   dim3(192), 0, stream, ws);
  hipLaunchKernelGGL(k_phase1,  dim3(CCH),  dim3(64),  0, stream, tracks, ws);
  hipLaunchKernelGGL(k_scanz_a, dim3(GRP),  dim3(256), 0, stream, ws);
  hipLaunchKernelGGL(k_scanz_b, dim3(4),    dim3(64),  0, stream, ws);
  hipLaunchKernelGGL(k_scanz_c, dim3(GRP),  dim3(256), 0, stream, ws);
  hipLaunchKernelGGL(k_phase3,  dim3(CCH),  dim3(64),  0, stream, tracks, ws);
  hipLaunchKernelGGL(k_compose, dim3(NTR*16), dim3(64), 0, stream, ws);
  hipLaunchKernelGGL(k_smooth,  dim3(NTR),  dim3(256), 0, stream, ws);
  hipLaunchKernelGGL(k_mix1,    dim3(NWIN/4),  dim3(256), 0, stream, ws);
  hipLaunchKernelGGL(k_mix2,    dim3(S_LEN/64), dim3(256), 0, stream, ws, out);
}

// Round 15
// 448.794 us; speedup vs baseline: 1.3538x; 1.3538x over previous
//
#include <hip/hip_runtime.h>
#include <math.h>

// ---------------------------------------------------------------------------
// AdvancedMixConsole: 64 tracks x 131072 samples.
//   gain -> 6 biquads (chunk-parallel linear recurrence, 12-dim state)
//        -> compressor: parallel static gain; serial smoother over
//           WINDOW MAPS (max-affine); window maps tree-composed W=64->128
//        -> pan/mix (parallel, two-stage).
// R26: k_compose re-shaped LANE=OUTPUT-INDEX (was lane=pair): R25 measured
//      299us with 2.2e7 LDS bank conflicts (stride-2 lane reads = 4-way)
//      and 74MB writes (64-line scatter per store). Now: natural LDS
//      layout + 64-float front pad, lane m reads IE[m-k] stride-1
//      (conflict-free), SL/IL uniform broadcast, output = contiguous
//      129-float coalesced record. 64 pairs serial per 128-thread block.
// ---------------------------------------------------------------------------

#define S_LEN 131072
#define NTR   64
#define CCH   512          // chunks (biquad phase)
#define LCH   256          // samples per chunk
#define GRP   32           // level-2 scan groups
#define GCH   16           // chunks per group
#define SMW   128          // smoother window (after compose)
#define NWIN  1024         // composed windows per track
#define NST3  2048         // original 64-sample windows per track
#define WPC3  4            // windows per biquad chunk (LCH/SMW0)
#define RECF  68           // floats per original record
#define REC2  136          // floats per composed record (129 used)
#define SCH   64           // k_smooth steps per LDS chunk
#define NCH   16           // LDS chunks (1024/64)
#define CHF4  2176         // float4s per chunk (64*136/4 = 128*68/4)

typedef float v2f __attribute__((ext_vector_type(2)));

// ws offsets in floats (total ~73.3 MB)
#define OFF_Y    0ull              // [131072][64]      EQ output y, sample-major
#define OFF_CI   8388608ull        // [64][2048][68]    intercept records; composed in-place to [64][1024][136]
#define OFF_TV   8388608ull        // [131072][64]      tv (ALIASES CI; used after k_smooth)
#define OFF_QB   17302528ull       // [64][2048]        boundary q per composed window (1024 used)
#define OFF_W    17433600ull       // [64][2]           cos/sin pan weights
#define OFF_COEF 17433728ull       // [64][32]          biquad coeffs
#define OFF_COMP 17435776ull       // [64][128]         compressor consts + 65 W=64 slopes
#define OFF_A    17443968ull       // [64][144]         cascade transition matrix
#define OFF_M    17453184ull       // [64][144]         A^LCH
#define OFF_F    17462400ull       // [CCH][12][64]     zero-init chunk finals (track-minor)
#define OFF_Z    17855616ull       // [CCH][12][64]     chunk init states (track-minor)
#define OFF_GF   18248832ull       // [32][12][64]      group from-zero finals
#define OFF_GZ   18273408ull       // [32][12][64]      group initial states
#define OFF_M2   18297984ull       // [64][144]         (A^LCH)^16
#define OFF_CMP2 18307200ull       // [64][136]         129 W=128 slopes aa^j ar^(128-j)

// ---------------------------------------------------------------------------
__global__ __launch_bounds__(64) void k_setup(const float* __restrict__ mp,
                                              float* __restrict__ ws) {
  int n = threadIdx.x;
  if (n >= NTR) return;
  const float* p = mp + n * 26;
  auto dn = [&](int i, double lo, double hi) { return (double)p[i] * (hi - lo) + lo; };

  double gain_db = dn(0, -24.0, 24.0);
  double glin = pow(10.0, gain_db / 20.0);
  const double nyq = 21050.0;  // 44100//2 - 1000

  double fg[6] = {dn(1,-24,24), dn(4,-24,24), dn(7,-24,24), dn(10,-24,24), dn(13,-24,24), dn(16,-24,24)};
  double ff[6] = {dn(2,20,2000), dn(5,80,2000), dn(8,2000,8000), dn(11,8000,12000), dn(14,12000,nyq), dn(17,6000,nyq)};
  double fq[6] = {dn(3,0.1,5), dn(6,0.1,5), dn(9,0.1,5), dn(12,0.1,5), dn(15,0.1,5), dn(18,0.1,5)};

  double B0[6], B1[6], B2[6], A1[6], A2[6];
  for (int k = 0; k < 6; k++) {
    double A  = pow(10.0, fg[k] / 40.0);
    double w0 = 2.0 * M_PI * ff[k] / 44100.0;
    double cw = cos(w0), sw = sin(w0);
    double al = sw / (2.0 * fq[k]);
    double sA = sqrt(A);
    double b0, b1, b2, a0, a1, a2;
    if (k == 0) {           // low shelf
      b0 = A*((A+1)-(A-1)*cw + 2*sA*al);
      b1 = 2*A*((A-1)-(A+1)*cw);
      b2 = A*((A+1)-(A-1)*cw - 2*sA*al);
      a0 = (A+1)+(A-1)*cw + 2*sA*al;
      a1 = -2*((A-1)+(A+1)*cw);
      a2 = (A+1)+(A-1)*cw - 2*sA*al;
    } else if (k == 5) {    // high shelf
      b0 = A*((A+1)+(A-1)*cw + 2*sA*al);
      b1 = -2*A*((A-1)+(A+1)*cw);
      b2 = A*((A+1)+(A-1)*cw - 2*sA*al);
      a0 = (A+1)-(A-1)*cw + 2*sA*al;
      a1 = 2*((A-1)-(A+1)*cw);
      a2 = (A+1)-(A-1)*cw - 2*sA*al;
    } else {                // peak
      b0 = 1 + al*A; b1 = -2*cw; b2 = 1 - al*A;
      a0 = 1 + al/A; a1 = -2*cw; a2 = 1 - al/A;
    }
    B0[k] = b0/a0; B1[k] = b1/a0; B2[k] = b2/a0; A1[k] = a1/a0; A2[k] = a2/a0;
  }
  // fold input gain into stage-0 numerator
  B0[0] *= glin; B1[0] *= glin; B2[0] *= glin;

  float* cf = ws + OFF_COEF + n * 32;
  for (int k = 0; k < 6; k++) {
    cf[k*5+0] = (float)B0[k]; cf[k*5+1] = (float)B1[k]; cf[k*5+2] = (float)B2[k];
    cf[k*5+3] = (float)A1[k]; cf[k*5+4] = (float)A2[k];
  }

  // compressor + pan constants
  double T = dn(19,-60,0), R = dn(20,1,10), atk = dn(21,1,1000), rel = dn(22,1,1000);
  double Kn = dn(23,3,24), mk = dn(24,0,24);
  double a_a = exp(-1.0 / (44100.0 * atk * 0.001));
  double a_r = exp(-1.0 / (44100.0 * rel * 0.001));
  double s   = (a_a < a_r) ? 1.0 : -1.0;     // q = s*p makes the recurrence pure-max
  double kca = s * (1.0 - a_a), kcr = s * (1.0 - a_r);
  double invR = 1.0 / R;
  const double K10 = 0.16609640474436813;    // log2(10)/20
  double theta = (double)p[25] * (M_PI / 2.0);

  float* cm = ws + OFF_COMP + n * 128;
  cm[0] = (float)a_a;  cm[1] = (float)a_r;  cm[2] = (float)kca; cm[3] = (float)kcr;
  cm[4] = (float)T;    cm[5] = (float)(Kn * 0.5);
  cm[6] = (float)(1.0 - invR);
  cm[7] = (float)((1.0 - invR) / (2.0 * Kn));
  cm[8] = (float)(mk * K10);   cm[9] = (float)(s * K10);
  cm[10] = (float)cos(theta);  cm[11] = (float)sin(theta);
  // 65 W=64 slopes aa^j ar^(64-j) — incremental (2 pow + 64 fmul)
  {
    double sj = pow(a_r, 64.0);
    double ratio = a_a / a_r;
    for (int j = 0; j <= 64; j++) { cm[16+j] = (float)sj; sj *= ratio; }
  }
  // 129 W=128 slopes aa^j ar^(128-j)
  {
    float* c2t = ws + OFF_CMP2 + (size_t)n*REC2;
    double sj = pow(a_r, 128.0);
    double ratio = a_a / a_r;
    for (int j = 0; j <= 128; j++) { c2t[j] = (float)sj; sj *= ratio; }
  }

  float* wp = ws + OFF_W + n*2;
  wp[0] = (float)cos(theta); wp[1] = (float)sin(theta);

  // homogeneous (x=0) cascade transition matrix, state = [s1_1,s2_1,...,s1_6,s2_6]
  double Am[12][12], yv[12], ny[12];
  for (int r = 0; r < 12; r++) { yv[r] = 0; for (int c = 0; c < 12; c++) Am[r][c] = 0; }
  for (int k = 0; k < 6; k++) {
    for (int c = 0; c < 12; c++) ny[c] = B0[k] * yv[c];
    ny[2*k] += 1.0;                                  // y_k = b0*y_{k-1} + s1_k
    for (int c = 0; c < 12; c++) Am[2*k][c]   = B1[k]*yv[c] - A1[k]*ny[c];
    Am[2*k][2*k+1] += 1.0;                           // + s2_k
    for (int c = 0; c < 12; c++) Am[2*k+1][c] = B2[k]*yv[c] - A2[k]*ny[c];
    for (int c = 0; c < 12; c++) yv[c] = ny[c];
  }
  float* Aw = ws + OFF_A + n * 144;
  for (int r = 0; r < 12; r++)
    for (int c = 0; c < 12; c++) Aw[r*12+c] = (float)Am[r][c];
}

// ---------------------------------------------------------------------------
// 12 squarings: store A^256 (=A^LCH) after 8, A^4096 (=(A^LCH)^16) after 12.
__global__ __launch_bounds__(192) void k_matpow(float* __restrict__ ws) {
  __shared__ float As[144];
  int n = blockIdx.x, t = threadIdx.x;
  int r = t / 12, c = t % 12;
  if (t < 144) As[t] = ws[OFF_A + (size_t)n*144 + t];
  __syncthreads();
  for (int it = 0; it < 12; ++it) {
    float acc = 0.f;
    if (t < 144) {
      #pragma unroll
      for (int k = 0; k < 12; k++) acc += As[r*12+k] * As[k*12+c];
    }
    __syncthreads();
    if (t < 144) As[t] = acc;
    __syncthreads();
    if (it == 7 && t < 144) ws[OFF_M + (size_t)n*144 + t] = As[t];   // A^256
  }
  if (t < 144) ws[OFF_M2 + (size_t)n*144 + t] = As[t];               // A^4096
}

// ---------------------------------------------------------------------------
__device__ __forceinline__ void load_coefs(const float* cf, float* b0, v2f* bb, v2f* naa) {
  #pragma unroll
  for (int k = 0; k < 6; k++) {
    b0[k]  = cf[k*5+0];
    bb[k]  = (v2f){cf[k*5+1], cf[k*5+2]};
    naa[k] = (v2f){-cf[k*5+3], -cf[k*5+4]};
  }
}

__device__ __forceinline__ float cascade_step(float x, float* b0, v2f* bb, v2f* naa, v2f* st) {
  #pragma unroll
  for (int k = 0; k < 6; k++) {
    float y  = fmaf(b0[k], x, st[k].x);
    v2f upd  = __builtin_elementwise_fma(bb[k], (v2f){x, x}, (v2f){st[k].y, 0.f});
    st[k]    = __builtin_elementwise_fma(naa[k], (v2f){y, y}, upd);
    x = y;
  }
  return x;
}

// phase 1: zero-init chunk finals
__global__ __launch_bounds__(64) void k_phase1(const float* __restrict__ tracks,
                                               float* __restrict__ ws) {
  int j = blockIdx.x, n = threadIdx.x;
  float b0[6]; v2f bb[6], naa[6];
  load_coefs(ws + OFF_COEF + n*32, b0, bb, naa);
  v2f st[6];
  #pragma unroll
  for (int k = 0; k < 6; k++) st[k] = (v2f){0.f, 0.f};
  const float4* xp = (const float4*)(tracks + (size_t)n*S_LEN + (size_t)j*LCH);
  for (int i4 = 0; i4 < LCH/4; ++i4) {
    float4 xq = xp[i4];
    float xs[4] = {xq.x, xq.y, xq.z, xq.w};
    #pragma unroll
    for (int u = 0; u < 4; u++) (void)cascade_step(xs[u], b0, bb, naa, st);
  }
  // track-minor layout [j][r][64]: 12 coalesced scalar stores
  float* f = ws + OFF_F + (size_t)j*(12*NTR) + n;
  #pragma unroll
  for (int k = 0; k < 6; k++) { f[(2*k)*64] = st[k].x; f[(2*k+1)*64] = st[k].y; }
}

// ---------------------------------------------------------------------------
// Blocked scan machinery (R21). Quad structure: 4 lanes per track instance.
__device__ __forceinline__ float qperm(float x, const int sel) {
  int xi = __float_as_int(x);
  int yi;
  switch (sel) {   // lane j receives from lane (j+k)&3 within its quad
    case 1:  yi = __builtin_amdgcn_update_dpp(xi, xi, 0x39, 0xf, 0xf, false); break; // [1,2,3,0]
    case 2:  yi = __builtin_amdgcn_update_dpp(xi, xi, 0x4E, 0xf, 0xf, false); break; // [2,3,0,1]
    default: yi = __builtin_amdgcn_update_dpp(xi, xi, 0x93, 0xf, 0xf, false); break; // [3,0,1,2]
  }
  return __int_as_float(yi);
}

// 36 named M scalars, columns in quad-rotation order (rows 3*sub..3*sub+2).
#define M_DECL(MBASE)                                                         \
  const int c0 = 3*((sub + 0) & 3), c1 = 3*((sub + 1) & 3),                   \
            c2 = 3*((sub + 2) & 3), c3 = 3*((sub + 3) & 3);                   \
  const float* Mb = (MBASE) + (3*sub)*12;                                     \
  float m0_0_0 = Mb[0*12+c0+0], m0_0_1 = Mb[1*12+c0+0], m0_0_2 = Mb[2*12+c0+0];\
  float m0_1_0 = Mb[0*12+c0+1], m0_1_1 = Mb[1*12+c0+1], m0_1_2 = Mb[2*12+c0+1];\
  float m0_2_0 = Mb[0*12+c0+2], m0_2_1 = Mb[1*12+c0+2], m0_2_2 = Mb[2*12+c0+2];\
  float m1_0_0 = Mb[0*12+c1+0], m1_0_1 = Mb[1*12+c1+0], m1_0_2 = Mb[2*12+c1+0];\
  float m1_1_0 = Mb[0*12+c1+1], m1_1_1 = Mb[1*12+c1+1], m1_1_2 = Mb[2*12+c1+1];\
  float m1_2_0 = Mb[0*12+c1+2], m1_2_1 = Mb[1*12+c1+2], m1_2_2 = Mb[2*12+c1+2];\
  float m2_0_0 = Mb[0*12+c2+0], m2_0_1 = Mb[1*12+c2+0], m2_0_2 = Mb[2*12+c2+0];\
  float m2_1_0 = Mb[0*12+c2+1], m2_1_1 = Mb[1*12+c2+1], m2_1_2 = Mb[2*12+c2+1];\
  float m2_2_0 = Mb[0*12+c2+2], m2_2_1 = Mb[1*12+c2+2], m2_2_2 = Mb[2*12+c2+2];\
  float m3_0_0 = Mb[0*12+c3+0], m3_0_1 = Mb[1*12+c3+0], m3_0_2 = Mb[2*12+c3+0];\
  float m3_1_0 = Mb[0*12+c3+1], m3_1_1 = Mb[1*12+c3+1], m3_1_2 = Mb[2*12+c3+1];\
  float m3_2_0 = Mb[0*12+c3+2], m3_2_1 = Mb[1*12+c3+2], m3_2_2 = Mb[2*12+c3+2];

// one scan step: z = M z + f, f at (FP)[0],[64],[128]
#define SCAN_STEP(FP)                                                         \
  {                                                                           \
    float t10 = qperm(z0,1), t11 = qperm(z1,1), t12 = qperm(z2,1);            \
    float t20 = qperm(z0,2), t21 = qperm(z1,2), t22 = qperm(z2,2);            \
    float t30 = qperm(z0,3), t31 = qperm(z1,3), t32 = qperm(z2,3);            \
    float a0 = (FP)[0], a1 = (FP)[64], a2 = (FP)[128];                        \
    a0 = fmaf(m0_0_0, z0, a0);  a1 = fmaf(m0_0_1, z0, a1);  a2 = fmaf(m0_0_2, z0, a2);  \
    a0 = fmaf(m0_1_0, z1, a0);  a1 = fmaf(m0_1_1, z1, a1);  a2 = fmaf(m0_1_2, z1, a2);  \
    a0 = fmaf(m0_2_0, z2, a0);  a1 = fmaf(m0_2_1, z2, a1);  a2 = fmaf(m0_2_2, z2, a2);  \
    a0 = fmaf(m1_0_0, t10, a0); a1 = fmaf(m1_0_1, t10, a1); a2 = fmaf(m1_0_2, t10, a2); \
    a0 = fmaf(m1_1_0, t11, a0); a1 = fmaf(m1_1_1, t11, a1); a2 = fmaf(m1_1_2, t11, a2); \
    a0 = fmaf(m1_2_0, t12, a0); a1 = fmaf(m1_2_1, t12, a1); a2 = fmaf(m1_2_2, t12, a2); \
    a0 = fmaf(m2_0_0, t20, a0); a1 = fmaf(m2_0_1, t20, a1); a2 = fmaf(m2_0_2, t20, a2); \
    a0 = fmaf(m2_1_0, t21, a0); a1 = fmaf(m2_1_1, t21, a1); a2 = fmaf(m2_1_2, t21, a2); \
    a0 = fmaf(m2_2_0, t22, a0); a1 = fmaf(m2_2_1, t22, a1); a2 = fmaf(m2_2_2, t22, a2); \
    a0 = fmaf(m3_0_0, t30, a0); a1 = fmaf(m3_0_1, t30, a1); a2 = fmaf(m3_0_2, t30, a2); \
    a0 = fmaf(m3_1_0, t31, a0); a1 = fmaf(m3_1_1, t31, a1); a2 = fmaf(m3_1_2, t31, a2); \
    a0 = fmaf(m3_2_0, t32, a0); a1 = fmaf(m3_2_1, t32, a1); a2 = fmaf(m3_2_2, t32, a2); \
    z0 = a0; z1 = a1; z2 = a2;                                                \
  }

// level-1: per-group from-zero finals (4-wave TLP hides reloads).
__global__ __launch_bounds__(256, 1) void k_scanz_a(float* __restrict__ ws) {
  const int tid = threadIdx.x;
  const int sub = tid & 3;
  const int n   = tid >> 2;          // track 0..63
  const int g   = blockIdx.x;        // group 0..31
  M_DECL(ws + OFF_M + (size_t)n*144)
  float z0 = 0.f, z1 = 0.f, z2 = 0.f;
  const float* __restrict__ fb = ws + OFF_F + (size_t)(g*GCH)*768 + (3*sub)*64 + n;
  #pragma unroll 4
  for (int k = 0; k < GCH; ++k) SCAN_STEP(fb + (size_t)k*768)
  float* gf = ws + OFF_GF + (size_t)g*768 + (3*sub)*64 + n;
  gf[0] = z0; gf[64] = z1; gf[128] = z2;
}

// level-2: serial scan over 32 group boundaries with M16=(A^LCH)^16.
__global__ __launch_bounds__(64, 1) void k_scanz_b(float* __restrict__ ws) {
  const int l   = threadIdx.x;
  const int sub = l & 3;
  const int n   = blockIdx.x*16 + (l >> 2);
  M_DECL(ws + OFF_M2 + (size_t)n*144)
  float z0 = 0.f, z1 = 0.f, z2 = 0.f;
  const float* __restrict__ fb = ws + OFF_GF + (3*sub)*64 + n;
  float*       __restrict__  zb = ws + OFF_GZ + (3*sub)*64 + n;
  for (int G = 0; G < GRP; ++G) {
    float* zp = zb + (size_t)G*768;
    zp[0] = z0; zp[64] = z1; zp[128] = z2;
    SCAN_STEP(fb + (size_t)G*768)
  }
}

// level-3: re-scan each group from its correct initial state.
__global__ __launch_bounds__(256, 1) void k_scanz_c(float* __restrict__ ws) {
  const int tid = threadIdx.x;
  const int sub = tid & 3;
  const int n   = tid >> 2;
  const int g   = blockIdx.x;
  M_DECL(ws + OFF_M + (size_t)n*144)
  const float* gz = ws + OFF_GZ + (size_t)g*768 + (3*sub)*64 + n;
  float z0 = gz[0], z1 = gz[64], z2 = gz[128];
  const float* __restrict__ fb = ws + OFF_F + (size_t)(g*GCH)*768 + (3*sub)*64 + n;
  float*       __restrict__  zb = ws + OFF_Z + (size_t)(g*GCH)*768 + (3*sub)*64 + n;
  #pragma unroll 4
  for (int k = 0; k < GCH; ++k) {
    float* zp = zb + (size_t)k*768;
    zp[0] = z0; zp[64] = z1; zp[128] = z2;
    SCAN_STEP(fb + (size_t)k*768)
  }
}

// phase 3: correct-init EQ; per-sample static gain; per-64-sample-window
// composed max-affine intercepts I[0..64]; 272B records [track][step][68].
__global__ __launch_bounds__(64, 1) void k_phase3(const float* __restrict__ tracks,
                                                  float* __restrict__ ws) {
  int j = blockIdx.x, n = threadIdx.x;
  float b0[6]; v2f bb[6], naa[6];
  load_coefs(ws + OFF_COEF + n*32, b0, bb, naa);
  const float* cm = ws + OFF_COMP + n*128;
  float a_a = cm[0], a_r = cm[1], kca = cm[2], kcr = cm[3];
  float T = cm[4], hK = cm[5], cg1 = cm[6], cg2 = cm[7];
  v2f st[6];
  const float* zp = ws + OFF_Z + (size_t)j*(12*NTR) + n;   // track-minor: 12 coalesced loads
  #pragma unroll
  for (int k = 0; k < 6; k++) st[k] = (v2f){zp[(2*k)*64], zp[(2*k+1)*64]};

  const float4* xp = (const float4*)(tracks + (size_t)n*S_LEN + (size_t)j*LCH);
  float* yb = ws + OFF_Y + (size_t)j*LCH*64 + n;                        // [sample][track]
  float* cw = ws + OFF_CI + (size_t)n*(NST3*RECF) + (size_t)j*WPC3*RECF;

  for (int w = 0; w < WPC3; ++w) {
    float I[65];
    I[0] = 0.f;
    #pragma unroll
    for (int jj = 1; jj < 65; ++jj) I[jj] = -1e30f;
    #pragma unroll
    for (int i4 = 0; i4 < 16; ++i4) {
      float4 xq = xp[w*16 + i4];
      float xs[4] = {xq.x, xq.y, xq.z, xq.w};
      #pragma unroll
      for (int u = 0; u < 4; ++u) {
        const int i = i4*4 + u;
        float y = cascade_step(xs[u], b0, bb, naa, st);
        yb[(w*64 + i)*64] = y;
        float v   = fabsf(y) + 1e-8f;
        float xdb = 6.020599913279624f * __log2f(v);
        float d   = xdb - T;
        float dk  = d + hK;
        float gg  = (d > hK) ? (cg1*d) : (cg2*dk*dk);
        gg = (d < -hK) ? 0.f : gg;
        float ca = kca*gg, cr = kcr*gg;
        // compose one sample into the window map (descending j, in place)
        #pragma unroll
        for (int jj = 64; jj >= 0; --jj) {
          if (jj <= i+1) {
            float up = (jj > 0) ? fmaf(a_a, I[jj-1], ca) : -1e30f;
            I[jj] = fmaxf(up, fmaf(a_r, I[jj], cr));
          }
        }
      }
    }
    float4* cq = (float4*)(cw + (size_t)w*RECF);
    #pragma unroll
    for (int r = 0; r < 16; ++r)
      cq[r] = make_float4(I[4*r], I[4*r+1], I[4*r+2], I[4*r+3]);
    (cw + (size_t)w*RECF)[64] = I[64];
    (cw + (size_t)w*RECF)[65] = -1e30f;
    (cw + (size_t)w*RECF)[66] = -1e30f;
    (cw + (size_t)w*RECF)[67] = -1e30f;
  }
}

// ---------------------------------------------------------------------------
// (max,+) window composition: pairs of 64-window maps -> 128-window maps.
// Block = 128 threads; LANE = OUTPUT INDEX m (R25's lane=pair had 4-way
// LDS conflicts + 64-line write scatter -> 299us). Records staged in
// NATURAL layout with a 64-float front pad (negative m-k reads land in
// dead pad, discarded by the validity select). Per pair (serial, 64/block):
// lane m: acc = max_k SL[k]*IE[m-k] + IL[k] — IE reads stride-1 across
// lanes (conflict-free), SL/IL uniform broadcast; output = contiguous
// 129-float coalesced record written in-place.
__global__ __launch_bounds__(128, 1) void k_compose(float* __restrict__ ws) {
  __shared__ float L[64 + 128*RECF];     // pad + 8704 natural-layout floats
  __shared__ float SL[68];
  const int t   = threadIdx.x;           // 0..127 = output index m
  const int n   = blockIdx.x >> 4;       // track
  const int seg = blockIdx.x & 15;       // 64-pair segment
  float* gbase = ws + OFF_CI + (size_t)n*(NST3*RECF) + (size_t)seg*(128*RECF);

  // stage 128 records linearly (no transpose); pad stays garbage (discarded)
  {
    float4* d4 = (float4*)&L[64];
    const float4* s4 = (const float4*)gbase;
    for (int i = t; i < 128*RECF/4; i += 128) d4[i] = s4[i];
  }
  for (int i = t; i <= 64; i += 128)
    SL[i] = ws[OFF_COMP + (size_t)n*128 + 16 + i];
  __syncthreads();

  for (int p = 0; p < 64; ++p) {
    const float* IE = &L[64 + (2*p)*RECF];     // early record (+64 pad base)
    const float* IL = &L[64 + (2*p+1)*RECF];   // late record
    float acc = -1e30f;
    #pragma unroll 13
    for (int k = 0; k <= 64; ++k) {
      float v = fmaf(SL[k], IE[t - k], IL[k]); // t-k<0 reads pad (discarded)
      acc = ((unsigned)(t - k) <= 64u) ? fmaxf(acc, v) : acc;
    }
    float* gout = gbase + (size_t)p*REC2;
    gout[t] = acc;                              // coalesced 128-float store
    if (t == 0) gout[128] = fmaf(SL[64], IE[64], IL[64]);  // m=128 term
  }
}

// ---------------------------------------------------------------------------
// serial max-affine smoother over COMPOSED W=128 maps. 1024 steps/track.
// Lane l owns slopes 2l,2l+1 (regs) + uniform term 128. Per step:
// ds_read_b64 + uniform read, 3 fma, max3, 6-stage fused DPP reduce,
// readlane -> SGPR q. 8-step A/B banks amortize lgkmcnt. Producer waves
// 1-3 double-buffer 64-record (34.8KB) chunks.
#define KSTEP2(IV, UV, SS)                                                    \
  {                                                                           \
    float f0  = fmaf(Sv0, qs, (IV).x);                                        \
    float f1  = fmaf(Sv1, qs, (IV).y);                                        \
    float fu  = fmaf(S128v, qs, (UV));                                        \
    float t   = fmaxf(fmaxf(f0, f1), fu);                                     \
    asm("s_nop 1\n\t"                                                         \
        "v_max_f32_dpp %0, %0, %0 row_shr:1 row_mask:0xf bank_mask:0xf\n\t"   \
        "s_nop 1\n\t"                                                         \
        "v_max_f32_dpp %0, %0, %0 row_shr:2 row_mask:0xf bank_mask:0xf\n\t"   \
        "s_nop 1\n\t"                                                         \
        "v_max_f32_dpp %0, %0, %0 row_shr:4 row_mask:0xf bank_mask:0xf\n\t"   \
        "s_nop 1\n\t"                                                         \
        "v_max_f32_dpp %0, %0, %0 row_shr:8 row_mask:0xf bank_mask:0xf\n\t"   \
        "s_nop 1\n\t"                                                         \
        "v_max_f32_dpp %0, %0, %0 row_bcast:15 row_mask:0xa bank_mask:0xf\n\t"\
        "s_nop 1\n\t"                                                         \
        "v_max_f32_dpp %0, %0, %0 row_bcast:31 row_mask:0xc bank_mask:0xf\n\t"\
        "s_nop 1"                                                             \
        : "+v"(t));                                                           \
    qs = __int_as_float(__builtin_amdgcn_readlane(__float_as_int(t), 63));    \
    qsave = ((SS) == l) ? qs : qsave;                                         \
  }

#define LD8B(B, S)                                                            \
  i##B##0 = *(const float2*)(Lb + ((S)+0)*REC2 + 2*l); u##B##0 = Lb[((S)+0)*REC2 + 128]; \
  i##B##1 = *(const float2*)(Lb + ((S)+1)*REC2 + 2*l); u##B##1 = Lb[((S)+1)*REC2 + 128]; \
  i##B##2 = *(const float2*)(Lb + ((S)+2)*REC2 + 2*l); u##B##2 = Lb[((S)+2)*REC2 + 128]; \
  i##B##3 = *(const float2*)(Lb + ((S)+3)*REC2 + 2*l); u##B##3 = Lb[((S)+3)*REC2 + 128]; \
  i##B##4 = *(const float2*)(Lb + ((S)+4)*REC2 + 2*l); u##B##4 = Lb[((S)+4)*REC2 + 128]; \
  i##B##5 = *(const float2*)(Lb + ((S)+5)*REC2 + 2*l); u##B##5 = Lb[((S)+5)*REC2 + 128]; \
  i##B##6 = *(const float2*)(Lb + ((S)+6)*REC2 + 2*l); u##B##6 = Lb[((S)+6)*REC2 + 128]; \
  i##B##7 = *(const float2*)(Lb + ((S)+7)*REC2 + 2*l); u##B##7 = Lb[((S)+7)*REC2 + 128];

#define KS8B(B, S)                                                            \
  KSTEP2(i##B##0, u##B##0, (S)+0)  KSTEP2(i##B##1, u##B##1, (S)+1)            \
  KSTEP2(i##B##2, u##B##2, (S)+2)  KSTEP2(i##B##3, u##B##3, (S)+3)            \
  KSTEP2(i##B##4, u##B##4, (S)+4)  KSTEP2(i##B##5, u##B##5, (S)+5)            \
  KSTEP2(i##B##6, u##B##6, (S)+6)  KSTEP2(i##B##7, u##B##7, (S)+7)

__global__ __launch_bounds__(256, 1) void k_smooth(float* __restrict__ ws) {
  __shared__ float buf[2][SCH*REC2];        // 2 x 34816 B
  const int n = blockIdx.x;
  const int tid = threadIdx.x;
  const int wave = tid >> 6, l = tid & 63;
  const float4* __restrict__ base4 =
      (const float4*)(ws + OFF_CI) + (size_t)n*(NST3*RECF/4);

  // preload chunk 0 (all threads)
  {
    const float4* s4 = base4;
    float4* d4 = (float4*)&buf[0][0];
    for (int i = tid; i < CHF4; i += 256) d4[i] = s4[i];
  }
  __syncthreads();

  const float* c2p = ws + OFF_CMP2 + (size_t)n*REC2;
  const float Sv0   = c2p[2*l];
  const float Sv1   = c2p[2*l + 1];
  const float S128v = c2p[128];
  float qs = 0.f;
  float* qt = ws + OFF_QB + (size_t)n * NST3;
  if (wave == 0) __builtin_amdgcn_s_setprio(3);   // critical serial wave

  for (int c2 = 0; c2 < NCH; ++c2) {
    if (wave != 0) {
      if (c2 + 1 < NCH) {
        const float4* src = base4 + (size_t)(c2+1)*CHF4;
        float4* dst = (float4*)&buf[(c2+1) & 1][0];
        const int p = tid - 64;               // 0..191
        #pragma unroll
        for (int r = 0; r < 3; ++r) {
          int i0 = p + r*768;
          float4 a = src[i0];                 // loads unguarded (global pad)
          float4 b = src[i0 + 192];
          float4 cc = src[i0 + 384];
          float4 d = src[i0 + 576];
          if (i0       < CHF4) dst[i0]       = a;
          if (i0 + 192 < CHF4) dst[i0 + 192] = b;
          if (i0 + 384 < CHF4) dst[i0 + 384] = cc;
          if (i0 + 576 < CHF4) dst[i0 + 576] = d;
        }
      }
    } else {
      const float* Lb = &buf[c2 & 1][0];
      float qsave = 0.f;
      float2 iA0,iA1,iA2,iA3,iA4,iA5,iA6,iA7;
      float  uA0,uA1,uA2,uA3,uA4,uA5,uA6,uA7;
      float2 iB0,iB1,iB2,iB3,iB4,iB5,iB6,iB7;
      float  uB0,uB1,uB2,uB3,uB4,uB5,uB6,uB7;
      LD8B(A, 0)                               // steps 0..7
      for (int s = 0; s < SCH; s += 16) {
        LD8B(B, s+8)                           // steps s+8..s+15
        KS8B(A, s)                             // steps s..s+7
        if (s + 16 < SCH) { LD8B(A, s+16) }    // steps s+16..s+23
        KS8B(B, s+8)                           // steps s+8..s+15
      }
      qt[c2*SCH + l] = qsave;                  // lane l kept step l of chunk
    }
    __syncthreads();
  }
}

// tv = y * 10^((mk - p)/20): exact 128-step reconstruction from boundary q.
// lanes = tracks -> fully coalesced y/tv rows.
__global__ __launch_bounds__(256) void k_mix1(float* __restrict__ ws) {
  const int n  = threadIdx.x & 63;
  const int kk = blockIdx.x*4 + (threadIdx.x >> 6);
  const float* cm = ws + OFF_COMP + n*128;
  const float aa = cm[0], ar = cm[1], kca = cm[2], kcr = cm[3];
  const float T = cm[4], hK = cm[5], cg1 = cm[6], cg2 = cm[7];
  const float mkK = cm[8], sK = cm[9];
  const float* __restrict__ yb  = ws + OFF_Y;
  float* __restrict__       tvb = ws + OFF_TV;
  float q = (kk > 0) ? ws[OFF_QB + (size_t)n*NST3 + (kk-1)] : 0.f;
  #pragma unroll 8
  for (int i = 0; i < SMW; ++i) {
    float y = yb[(size_t)(kk*SMW + i)*64 + n];
    float v   = fabsf(y) + 1e-8f;
    float xdb = 6.020599913279624f * __log2f(v);
    float d   = xdb - T;
    float dk  = d + hK;
    float gg  = (d > hK) ? (cg1*d) : (cg2*dk*dk);
    gg = (d < -hK) ? 0.f : gg;
    q = fmaxf(fmaf(aa, q, kca*gg), fmaf(ar, q, kcr*gg));
    float sc = exp2f(fmaf(-sK, q, mkK));
    tvb[(size_t)(kk*SMW + i)*64 + n] = y * sc;
  }
}

// 16-track pan reduction -> out[b][2][S]
__global__ __launch_bounds__(256) void k_mix2(const float* __restrict__ ws,
                                              float* __restrict__ out) {
  const int b = threadIdx.x & 3;
  const int s = blockIdx.x*64 + (threadIdx.x >> 2);
  const float* __restrict__ tvb = ws + OFF_TV;
  const float2* __restrict__ wp = (const float2*)(ws + OFF_W);
  float accL = 0.f, accR = 0.f;
  const int n0 = b*16;
  #pragma unroll
  for (int t = 0; t < 16; ++t) {
    float tv = tvb[(size_t)s*64 + n0 + t];
    float2 w2 = wp[n0 + t];
    accL = fmaf(w2.x, tv, accL);
    accR = fmaf(w2.y, tv, accR);
  }
  out[(size_t)(b*2 + 0)*S_LEN + s] = accL;
  out[(size_t)(b*2 + 1)*S_LEN + s] = accR;
}

// ---------------------------------------------------------------------------
extern "C" void kernel_launch(void* const* d_in, const int* in_sizes, int n_in,
                              void* d_out, int out_size, void* d_ws, size_t ws_size,
                              hipStream_t stream) {
  const float* tracks = (const float*)d_in[0];
  const float* mp     = (const float*)d_in[1];
  float* ws  = (float*)d_ws;
  float* out = (float*)d_out;

  hipLaunchKernelGGL(k_setup,   dim3(1),    dim3(64),  0, stream, mp, ws);
  hipLaunchKernelGGL(k_matpow,  dim3(64),   dim3(192), 0, stream, ws);
  hipLaunchKernelGGL(k_phase1,  dim3(CCH),  dim3(64),  0, stream, tracks, ws);
  hipLaunchKernelGGL(k_scanz_a, dim3(GRP),  dim3(256), 0, stream, ws);
  hipLaunchKernelGGL(k_scanz_b, dim3(4),    dim3(64),  0, stream, ws);
  hipLaunchKernelGGL(k_scanz_c, dim3(GRP),  dim3(256), 0, stream, ws);
  hipLaunchKernelGGL(k_phase3,  dim3(CCH),  dim3(64),  0, stream, tracks, ws);
  hipLaunchKernelGGL(k_compose, dim3(NTR*16), dim3(128), 0, stream, ws);
  hipLaunchKernelGGL(k_smooth,  dim3(NTR),  dim3(256), 0, stream, ws);
  hipLaunchKernelGGL(k_mix1,    dim3(NWIN/4),  dim3(256), 0, stream, ws);
  hipLaunchKernelGGL(k_mix2,    dim3(S_LEN/64), dim3(256), 0, stream, ws, out);
}

// Round 16
// 375.767 us; speedup vs baseline: 1.6169x; 1.1943x over previous
//
#include <hip/hip_runtime.h>
#include <math.h>

// ---------------------------------------------------------------------------
// AdvancedMixConsole: 64 tracks x 131072 samples.
//   gain -> 6 biquads (chunk-parallel linear recurrence, 12-dim state)
//        -> compressor: parallel static gain; serial smoother over W=128
//           max-affine WINDOW MAPS built DIRECTLY in phase3
//        -> pan/mix (parallel, two-stage).
// R27: k_compose ELIMINATED (R26: 143us, LDS-issue floor ~55us for any
//      separate (max,+) conv kernel). phase3 builds W=128 maps (129 terms)
//      incrementally in registers — same algorithm, bigger I[]:
//      (a) the jj<=i+1 guard is dropped: untouched entries hold -1e30
//          which decays under the affine update (stays ~-1e29 == -inf
//          for the max); (b) 8 segments of 16 samples with static jj-caps
//          16..128 recover triangular-work savings with static unrolls.
//      smoother unchanged (1024 steps over REC2 records, ~65us measured).
// ---------------------------------------------------------------------------

#define S_LEN 131072
#define NTR   64
#define CCH   512          // chunks (biquad phase)
#define LCH   256          // samples per chunk
#define GRP   32           // level-2 scan groups
#define GCH   16           // chunks per group
#define SMW   128          // smoother window
#define NWIN  1024         // windows per track
#define WPC2  2            // windows per biquad chunk (LCH/SMW)
#define REC2  136          // floats per record (129 used)
#define SCH   64           // k_smooth steps per LDS chunk
#define NCH   16           // LDS chunks (1024/64)
#define CHF4  2176         // float4s per chunk (64*136/4)

typedef float v2f __attribute__((ext_vector_type(2)));

// ws offsets in floats (total ~73.3 MB)
#define OFF_Y    0ull              // [131072][64]      EQ output y, sample-major
#define OFF_CI   8388608ull        // [64][1024][136]   W=128 intercept records
#define OFF_TV   8388608ull        // [131072][64]      tv (ALIASES CI; used after k_smooth)
#define OFF_QB   17302528ull       // [64][2048]        boundary q per window (1024 used)
#define OFF_W    17433600ull       // [64][2]           cos/sin pan weights
#define OFF_COEF 17433728ull       // [64][32]          biquad coeffs
#define OFF_COMP 17435776ull       // [64][128]         compressor consts
#define OFF_A    17443968ull       // [64][144]         cascade transition matrix
#define OFF_M    17453184ull       // [64][144]         A^LCH
#define OFF_F    17462400ull       // [CCH][12][64]     zero-init chunk finals (track-minor)
#define OFF_Z    17855616ull       // [CCH][12][64]     chunk init states (track-minor)
#define OFF_GF   18248832ull       // [32][12][64]      group from-zero finals
#define OFF_GZ   18273408ull       // [32][12][64]      group initial states
#define OFF_M2   18297984ull       // [64][144]         (A^LCH)^16
#define OFF_CMP2 18307200ull       // [64][136]         129 W=128 slopes aa^j ar^(128-j)

// ---------------------------------------------------------------------------
__global__ __launch_bounds__(64) void k_setup(const float* __restrict__ mp,
                                              float* __restrict__ ws) {
  int n = threadIdx.x;
  if (n >= NTR) return;
  const float* p = mp + n * 26;
  auto dn = [&](int i, double lo, double hi) { return (double)p[i] * (hi - lo) + lo; };

  double gain_db = dn(0, -24.0, 24.0);
  double glin = pow(10.0, gain_db / 20.0);
  const double nyq = 21050.0;  // 44100//2 - 1000

  double fg[6] = {dn(1,-24,24), dn(4,-24,24), dn(7,-24,24), dn(10,-24,24), dn(13,-24,24), dn(16,-24,24)};
  double ff[6] = {dn(2,20,2000), dn(5,80,2000), dn(8,2000,8000), dn(11,8000,12000), dn(14,12000,nyq), dn(17,6000,nyq)};
  double fq[6] = {dn(3,0.1,5), dn(6,0.1,5), dn(9,0.1,5), dn(12,0.1,5), dn(15,0.1,5), dn(18,0.1,5)};

  double B0[6], B1[6], B2[6], A1[6], A2[6];
  for (int k = 0; k < 6; k++) {
    double A  = pow(10.0, fg[k] / 40.0);
    double w0 = 2.0 * M_PI * ff[k] / 44100.0;
    double cw = cos(w0), sw = sin(w0);
    double al = sw / (2.0 * fq[k]);
    double sA = sqrt(A);
    double b0, b1, b2, a0, a1, a2;
    if (k == 0) {           // low shelf
      b0 = A*((A+1)-(A-1)*cw + 2*sA*al);
      b1 = 2*A*((A-1)-(A+1)*cw);
      b2 = A*((A+1)-(A-1)*cw - 2*sA*al);
      a0 = (A+1)+(A-1)*cw + 2*sA*al;
      a1 = -2*((A-1)+(A+1)*cw);
      a2 = (A+1)+(A-1)*cw - 2*sA*al;
    } else if (k == 5) {    // high shelf
      b0 = A*((A+1)+(A-1)*cw + 2*sA*al);
      b1 = -2*A*((A-1)+(A+1)*cw);
      b2 = A*((A+1)+(A-1)*cw - 2*sA*al);
      a0 = (A+1)-(A-1)*cw + 2*sA*al;
      a1 = 2*((A-1)-(A+1)*cw);
      a2 = (A+1)-(A-1)*cw - 2*sA*al;
    } else {                // peak
      b0 = 1 + al*A; b1 = -2*cw; b2 = 1 - al*A;
      a0 = 1 + al/A; a1 = -2*cw; a2 = 1 - al/A;
    }
    B0[k] = b0/a0; B1[k] = b1/a0; B2[k] = b2/a0; A1[k] = a1/a0; A2[k] = a2/a0;
  }
  // fold input gain into stage-0 numerator
  B0[0] *= glin; B1[0] *= glin; B2[0] *= glin;

  float* cf = ws + OFF_COEF + n * 32;
  for (int k = 0; k < 6; k++) {
    cf[k*5+0] = (float)B0[k]; cf[k*5+1] = (float)B1[k]; cf[k*5+2] = (float)B2[k];
    cf[k*5+3] = (float)A1[k]; cf[k*5+4] = (float)A2[k];
  }

  // compressor + pan constants
  double T = dn(19,-60,0), R = dn(20,1,10), atk = dn(21,1,1000), rel = dn(22,1,1000);
  double Kn = dn(23,3,24), mk = dn(24,0,24);
  double a_a = exp(-1.0 / (44100.0 * atk * 0.001));
  double a_r = exp(-1.0 / (44100.0 * rel * 0.001));
  double s   = (a_a < a_r) ? 1.0 : -1.0;     // q = s*p makes the recurrence pure-max
  double kca = s * (1.0 - a_a), kcr = s * (1.0 - a_r);
  double invR = 1.0 / R;
  const double K10 = 0.16609640474436813;    // log2(10)/20
  double theta = (double)p[25] * (M_PI / 2.0);

  float* cm = ws + OFF_COMP + n * 128;
  cm[0] = (float)a_a;  cm[1] = (float)a_r;  cm[2] = (float)kca; cm[3] = (float)kcr;
  cm[4] = (float)T;    cm[5] = (float)(Kn * 0.5);
  cm[6] = (float)(1.0 - invR);
  cm[7] = (float)((1.0 - invR) / (2.0 * Kn));
  cm[8] = (float)(mk * K10);   cm[9] = (float)(s * K10);
  cm[10] = (float)cos(theta);  cm[11] = (float)sin(theta);
  // 129 W=128 slopes aa^j ar^(128-j) — incremental (2 pow + 128 fmul)
  {
    float* c2t = ws + OFF_CMP2 + (size_t)n*REC2;
    double sj = pow(a_r, 128.0);
    double ratio = a_a / a_r;
    for (int j = 0; j <= 128; j++) { c2t[j] = (float)sj; sj *= ratio; }
  }

  float* wp = ws + OFF_W + n*2;
  wp[0] = (float)cos(theta); wp[1] = (float)sin(theta);

  // homogeneous (x=0) cascade transition matrix, state = [s1_1,s2_1,...,s1_6,s2_6]
  double Am[12][12], yv[12], ny[12];
  for (int r = 0; r < 12; r++) { yv[r] = 0; for (int c = 0; c < 12; c++) Am[r][c] = 0; }
  for (int k = 0; k < 6; k++) {
    for (int c = 0; c < 12; c++) ny[c] = B0[k] * yv[c];
    ny[2*k] += 1.0;                                  // y_k = b0*y_{k-1} + s1_k
    for (int c = 0; c < 12; c++) Am[2*k][c]   = B1[k]*yv[c] - A1[k]*ny[c];
    Am[2*k][2*k+1] += 1.0;                           // + s2_k
    for (int c = 0; c < 12; c++) Am[2*k+1][c] = B2[k]*yv[c] - A2[k]*ny[c];
    for (int c = 0; c < 12; c++) yv[c] = ny[c];
  }
  float* Aw = ws + OFF_A + n * 144;
  for (int r = 0; r < 12; r++)
    for (int c = 0; c < 12; c++) Aw[r*12+c] = (float)Am[r][c];
}

// ---------------------------------------------------------------------------
// 12 squarings: store A^256 (=A^LCH) after 8, A^4096 (=(A^LCH)^16) after 12.
__global__ __launch_bounds__(192) void k_matpow(float* __restrict__ ws) {
  __shared__ float As[144];
  int n = blockIdx.x, t = threadIdx.x;
  int r = t / 12, c = t % 12;
  if (t < 144) As[t] = ws[OFF_A + (size_t)n*144 + t];
  __syncthreads();
  for (int it = 0; it < 12; ++it) {
    float acc = 0.f;
    if (t < 144) {
      #pragma unroll
      for (int k = 0; k < 12; k++) acc += As[r*12+k] * As[k*12+c];
    }
    __syncthreads();
    if (t < 144) As[t] = acc;
    __syncthreads();
    if (it == 7 && t < 144) ws[OFF_M + (size_t)n*144 + t] = As[t];   // A^256
  }
  if (t < 144) ws[OFF_M2 + (size_t)n*144 + t] = As[t];               // A^4096
}

// ---------------------------------------------------------------------------
__device__ __forceinline__ void load_coefs(const float* cf, float* b0, v2f* bb, v2f* naa) {
  #pragma unroll
  for (int k = 0; k < 6; k++) {
    b0[k]  = cf[k*5+0];
    bb[k]  = (v2f){cf[k*5+1], cf[k*5+2]};
    naa[k] = (v2f){-cf[k*5+3], -cf[k*5+4]};
  }
}

__device__ __forceinline__ float cascade_step(float x, float* b0, v2f* bb, v2f* naa, v2f* st) {
  #pragma unroll
  for (int k = 0; k < 6; k++) {
    float y  = fmaf(b0[k], x, st[k].x);
    v2f upd  = __builtin_elementwise_fma(bb[k], (v2f){x, x}, (v2f){st[k].y, 0.f});
    st[k]    = __builtin_elementwise_fma(naa[k], (v2f){y, y}, upd);
    x = y;
  }
  return x;
}

// phase 1: zero-init chunk finals
__global__ __launch_bounds__(64) void k_phase1(const float* __restrict__ tracks,
                                               float* __restrict__ ws) {
  int j = blockIdx.x, n = threadIdx.x;
  float b0[6]; v2f bb[6], naa[6];
  load_coefs(ws + OFF_COEF + n*32, b0, bb, naa);
  v2f st[6];
  #pragma unroll
  for (int k = 0; k < 6; k++) st[k] = (v2f){0.f, 0.f};
  const float4* xp = (const float4*)(tracks + (size_t)n*S_LEN + (size_t)j*LCH);
  for (int i4 = 0; i4 < LCH/4; ++i4) {
    float4 xq = xp[i4];
    float xs[4] = {xq.x, xq.y, xq.z, xq.w};
    #pragma unroll
    for (int u = 0; u < 4; u++) (void)cascade_step(xs[u], b0, bb, naa, st);
  }
  // track-minor layout [j][r][64]: 12 coalesced scalar stores
  float* f = ws + OFF_F + (size_t)j*(12*NTR) + n;
  #pragma unroll
  for (int k = 0; k < 6; k++) { f[(2*k)*64] = st[k].x; f[(2*k+1)*64] = st[k].y; }
}

// ---------------------------------------------------------------------------
// Blocked scan machinery (R21). Quad structure: 4 lanes per track instance.
__device__ __forceinline__ float qperm(float x, const int sel) {
  int xi = __float_as_int(x);
  int yi;
  switch (sel) {   // lane j receives from lane (j+k)&3 within its quad
    case 1:  yi = __builtin_amdgcn_update_dpp(xi, xi, 0x39, 0xf, 0xf, false); break; // [1,2,3,0]
    case 2:  yi = __builtin_amdgcn_update_dpp(xi, xi, 0x4E, 0xf, 0xf, false); break; // [2,3,0,1]
    default: yi = __builtin_amdgcn_update_dpp(xi, xi, 0x93, 0xf, 0xf, false); break; // [3,0,1,2]
  }
  return __int_as_float(yi);
}

// 36 named M scalars, columns in quad-rotation order (rows 3*sub..3*sub+2).
#define M_DECL(MBASE)                                                         \
  const int c0 = 3*((sub + 0) & 3), c1 = 3*((sub + 1) & 3),                   \
            c2 = 3*((sub + 2) & 3), c3 = 3*((sub + 3) & 3);                   \
  const float* Mb = (MBASE) + (3*sub)*12;                                     \
  float m0_0_0 = Mb[0*12+c0+0], m0_0_1 = Mb[1*12+c0+0], m0_0_2 = Mb[2*12+c0+0];\
  float m0_1_0 = Mb[0*12+c0+1], m0_1_1 = Mb[1*12+c0+1], m0_1_2 = Mb[2*12+c0+1];\
  float m0_2_0 = Mb[0*12+c0+2], m0_2_1 = Mb[1*12+c0+2], m0_2_2 = Mb[2*12+c0+2];\
  float m1_0_0 = Mb[0*12+c1+0], m1_0_1 = Mb[1*12+c1+0], m1_0_2 = Mb[2*12+c1+0];\
  float m1_1_0 = Mb[0*12+c1+1], m1_1_1 = Mb[1*12+c1+1], m1_1_2 = Mb[2*12+c1+1];\
  float m1_2_0 = Mb[0*12+c1+2], m1_2_1 = Mb[1*12+c1+2], m1_2_2 = Mb[2*12+c1+2];\
  float m2_0_0 = Mb[0*12+c2+0], m2_0_1 = Mb[1*12+c2+0], m2_0_2 = Mb[2*12+c2+0];\
  float m2_1_0 = Mb[0*12+c2+1], m2_1_1 = Mb[1*12+c2+1], m2_1_2 = Mb[2*12+c2+1];\
  float m2_2_0 = Mb[0*12+c2+2], m2_2_1 = Mb[1*12+c2+2], m2_2_2 = Mb[2*12+c2+2];\
  float m3_0_0 = Mb[0*12+c3+0], m3_0_1 = Mb[1*12+c3+0], m3_0_2 = Mb[2*12+c3+0];\
  float m3_1_0 = Mb[0*12+c3+1], m3_1_1 = Mb[1*12+c3+1], m3_1_2 = Mb[2*12+c3+1];\
  float m3_2_0 = Mb[0*12+c3+2], m3_2_1 = Mb[1*12+c3+2], m3_2_2 = Mb[2*12+c3+2];

// one scan step: z = M z + f, f at (FP)[0],[64],[128]
#define SCAN_STEP(FP)                                                         \
  {                                                                           \
    float t10 = qperm(z0,1), t11 = qperm(z1,1), t12 = qperm(z2,1);            \
    float t20 = qperm(z0,2), t21 = qperm(z1,2), t22 = qperm(z2,2);            \
    float t30 = qperm(z0,3), t31 = qperm(z1,3), t32 = qperm(z2,3);            \
    float a0 = (FP)[0], a1 = (FP)[64], a2 = (FP)[128];                        \
    a0 = fmaf(m0_0_0, z0, a0);  a1 = fmaf(m0_0_1, z0, a1);  a2 = fmaf(m0_0_2, z0, a2);  \
    a0 = fmaf(m0_1_0, z1, a0);  a1 = fmaf(m0_1_1, z1, a1);  a2 = fmaf(m0_1_2, z1, a2);  \
    a0 = fmaf(m0_2_0, z2, a0);  a1 = fmaf(m0_2_1, z2, a1);  a2 = fmaf(m0_2_2, z2, a2);  \
    a0 = fmaf(m1_0_0, t10, a0); a1 = fmaf(m1_0_1, t10, a1); a2 = fmaf(m1_0_2, t10, a2); \
    a0 = fmaf(m1_1_0, t11, a0); a1 = fmaf(m1_1_1, t11, a1); a2 = fmaf(m1_1_2, t11, a2); \
    a0 = fmaf(m1_2_0, t12, a0); a1 = fmaf(m1_2_1, t12, a1); a2 = fmaf(m1_2_2, t12, a2); \
    a0 = fmaf(m2_0_0, t20, a0); a1 = fmaf(m2_0_1, t20, a1); a2 = fmaf(m2_0_2, t20, a2); \
    a0 = fmaf(m2_1_0, t21, a0); a1 = fmaf(m2_1_1, t21, a1); a2 = fmaf(m2_1_2, t21, a2); \
    a0 = fmaf(m2_2_0, t22, a0); a1 = fmaf(m2_2_1, t22, a1); a2 = fmaf(m2_2_2, t22, a2); \
    a0 = fmaf(m3_0_0, t30, a0); a1 = fmaf(m3_0_1, t30, a1); a2 = fmaf(m3_0_2, t30, a2); \
    a0 = fmaf(m3_1_0, t31, a0); a1 = fmaf(m3_1_1, t31, a1); a2 = fmaf(m3_1_2, t31, a2); \
    a0 = fmaf(m3_2_0, t32, a0); a1 = fmaf(m3_2_1, t32, a1); a2 = fmaf(m3_2_2, t32, a2); \
    z0 = a0; z1 = a1; z2 = a2;                                                \
  }

// level-1: per-group from-zero finals (4-wave TLP hides reloads).
__global__ __launch_bounds__(256, 1) void k_scanz_a(float* __restrict__ ws) {
  const int tid = threadIdx.x;
  const int sub = tid & 3;
  const int n   = tid >> 2;          // track 0..63
  const int g   = blockIdx.x;        // group 0..31
  M_DECL(ws + OFF_M + (size_t)n*144)
  float z0 = 0.f, z1 = 0.f, z2 = 0.f;
  const float* __restrict__ fb = ws + OFF_F + (size_t)(g*GCH)*768 + (3*sub)*64 + n;
  #pragma unroll 4
  for (int k = 0; k < GCH; ++k) SCAN_STEP(fb + (size_t)k*768)
  float* gf = ws + OFF_GF + (size_t)g*768 + (3*sub)*64 + n;
  gf[0] = z0; gf[64] = z1; gf[128] = z2;
}

// level-2: serial scan over 32 group boundaries with M16=(A^LCH)^16.
__global__ __launch_bounds__(64, 1) void k_scanz_b(float* __restrict__ ws) {
  const int l   = threadIdx.x;
  const int sub = l & 3;
  const int n   = blockIdx.x*16 + (l >> 2);
  M_DECL(ws + OFF_M2 + (size_t)n*144)
  float z0 = 0.f, z1 = 0.f, z2 = 0.f;
  const float* __restrict__ fb = ws + OFF_GF + (3*sub)*64 + n;
  float*       __restrict__  zb = ws + OFF_GZ + (3*sub)*64 + n;
  for (int G = 0; G < GRP; ++G) {
    float* zp = zb + (size_t)G*768;
    zp[0] = z0; zp[64] = z1; zp[128] = z2;
    SCAN_STEP(fb + (size_t)G*768)
  }
}

// level-3: re-scan each group from its correct initial state.
__global__ __launch_bounds__(256, 1) void k_scanz_c(float* __restrict__ ws) {
  const int tid = threadIdx.x;
  const int sub = tid & 3;
  const int n   = tid >> 2;
  const int g   = blockIdx.x;
  M_DECL(ws + OFF_M + (size_t)n*144)
  const float* gz = ws + OFF_GZ + (size_t)g*768 + (3*sub)*64 + n;
  float z0 = gz[0], z1 = gz[64], z2 = gz[128];
  const float* __restrict__ fb = ws + OFF_F + (size_t)(g*GCH)*768 + (3*sub)*64 + n;
  float*       __restrict__  zb = ws + OFF_Z + (size_t)(g*GCH)*768 + (3*sub)*64 + n;
  #pragma unroll 4
  for (int k = 0; k < GCH; ++k) {
    float* zp = zb + (size_t)k*768;
    zp[0] = z0; zp[64] = z1; zp[128] = z2;
    SCAN_STEP(fb + (size_t)k*768)
  }
}

// ---------------------------------------------------------------------------
// phase 3: correct-init EQ; per-sample static gain; DIRECT W=128 window-map
// build. I[0..128] in registers (static indices only). No validity guard:
// untouched entries start at -1e30 and decay under the affine update —
// numerically -inf for the max. 8 segments x 16 samples with static jj-caps
// (16,32,...,128) recover triangular-work savings. Records written at
// REC2=136 stride: [track][1024][136], floats 0..128 used.
#define P3SEG(JJMAX)                                                          \
  for (int i4 = 0; i4 < 4; ++i4) {                                            \
    float4 xq = xp[w*32 + (soff >> 2) + i4];                                  \
    float xs[4] = {xq.x, xq.y, xq.z, xq.w};                                   \
    _Pragma("unroll")                                                         \
    for (int u = 0; u < 4; ++u) {                                             \
      float y = cascade_step(xs[u], b0, bb, naa, st);                         \
      yb[(w*128 + soff + i4*4 + u)*64] = y;                                   \
      float v   = fabsf(y) + 1e-8f;                                           \
      float xdb = 6.020599913279624f * __log2f(v);                            \
      float d   = xdb - T;                                                    \
      float dk  = d + hK;                                                     \
      float gg  = (d > hK) ? (cg1*d) : (cg2*dk*dk);                           \
      gg = (d < -hK) ? 0.f : gg;                                              \
      float ca = kca*gg, cr = kcr*gg;                                         \
      _Pragma("unroll")                                                       \
      for (int jj = (JJMAX); jj >= 1; --jj)                                   \
        I[jj] = fmaxf(fmaf(a_a, I[jj-1], ca), fmaf(a_r, I[jj], cr));          \
      I[0] = fmaf(a_r, I[0], cr);                                             \
    }                                                                         \
  }                                                                           \
  soff += 16;

__global__ __launch_bounds__(64, 1) void k_phase3(const float* __restrict__ tracks,
                                                  float* __restrict__ ws) {
  int j = blockIdx.x, n = threadIdx.x;
  float b0[6]; v2f bb[6], naa[6];
  load_coefs(ws + OFF_COEF + n*32, b0, bb, naa);
  const float* cm = ws + OFF_COMP + n*128;
  float a_a = cm[0], a_r = cm[1], kca = cm[2], kcr = cm[3];
  float T = cm[4], hK = cm[5], cg1 = cm[6], cg2 = cm[7];
  v2f st[6];
  const float* zp = ws + OFF_Z + (size_t)j*(12*NTR) + n;   // track-minor: 12 coalesced loads
  #pragma unroll
  for (int k = 0; k < 6; k++) st[k] = (v2f){zp[(2*k)*64], zp[(2*k+1)*64]};

  const float4* xp = (const float4*)(tracks + (size_t)n*S_LEN + (size_t)j*LCH);
  float* yb = ws + OFF_Y + (size_t)j*LCH*64 + n;                        // [sample][track]
  float* cw = ws + OFF_CI + (size_t)n*(NWIN*REC2) + (size_t)j*WPC2*REC2;

  for (int w = 0; w < WPC2; ++w) {
    float I[129];
    I[0] = 0.f;
    #pragma unroll
    for (int jj = 1; jj < 129; ++jj) I[jj] = -1e30f;
    int soff = 0;
    P3SEG(16)  P3SEG(32)  P3SEG(48)  P3SEG(64)
    P3SEG(80)  P3SEG(96)  P3SEG(112) P3SEG(128)

    float4* cq = (float4*)(cw + (size_t)w*REC2);
    #pragma unroll
    for (int r = 0; r < 32; ++r)
      cq[r] = make_float4(I[4*r], I[4*r+1], I[4*r+2], I[4*r+3]);
    (cw + (size_t)w*REC2)[128] = I[128];
  }
}

// ---------------------------------------------------------------------------
// serial max-affine smoother over W=128 maps. 1024 steps/track.
// Lane l owns slopes 2l,2l+1 (regs) + uniform term 128. Per step:
// ds_read_b64 + uniform read, 3 fma, max3, 6-stage fused DPP reduce,
// readlane -> SGPR q. 8-step A/B banks amortize lgkmcnt. Producer waves
// 1-3 double-buffer 64-record (34.8KB) chunks.
#define KSTEP2(IV, UV, SS)                                                    \
  {                                                                           \
    float f0  = fmaf(Sv0, qs, (IV).x);                                        \
    float f1  = fmaf(Sv1, qs, (IV).y);                                        \
    float fu  = fmaf(S128v, qs, (UV));                                        \
    float t   = fmaxf(fmaxf(f0, f1), fu);                                     \
    asm("s_nop 1\n\t"                                                         \
        "v_max_f32_dpp %0, %0, %0 row_shr:1 row_mask:0xf bank_mask:0xf\n\t"   \
        "s_nop 1\n\t"                                                         \
        "v_max_f32_dpp %0, %0, %0 row_shr:2 row_mask:0xf bank_mask:0xf\n\t"   \
        "s_nop 1\n\t"                                                         \
        "v_max_f32_dpp %0, %0, %0 row_shr:4 row_mask:0xf bank_mask:0xf\n\t"   \
        "s_nop 1\n\t"                                                         \
        "v_max_f32_dpp %0, %0, %0 row_shr:8 row_mask:0xf bank_mask:0xf\n\t"   \
        "s_nop 1\n\t"                                                         \
        "v_max_f32_dpp %0, %0, %0 row_bcast:15 row_mask:0xa bank_mask:0xf\n\t"\
        "s_nop 1\n\t"                                                         \
        "v_max_f32_dpp %0, %0, %0 row_bcast:31 row_mask:0xc bank_mask:0xf\n\t"\
        "s_nop 1"                                                             \
        : "+v"(t));                                                           \
    qs = __int_as_float(__builtin_amdgcn_readlane(__float_as_int(t), 63));    \
    qsave = ((SS) == l) ? qs : qsave;                                         \
  }

#define LD8B(B, S)                                                            \
  i##B##0 = *(const float2*)(Lb + ((S)+0)*REC2 + 2*l); u##B##0 = Lb[((S)+0)*REC2 + 128]; \
  i##B##1 = *(const float2*)(Lb + ((S)+1)*REC2 + 2*l); u##B##1 = Lb[((S)+1)*REC2 + 128]; \
  i##B##2 = *(const float2*)(Lb + ((S)+2)*REC2 + 2*l); u##B##2 = Lb[((S)+2)*REC2 + 128]; \
  i##B##3 = *(const float2*)(Lb + ((S)+3)*REC2 + 2*l); u##B##3 = Lb[((S)+3)*REC2 + 128]; \
  i##B##4 = *(const float2*)(Lb + ((S)+4)*REC2 + 2*l); u##B##4 = Lb[((S)+4)*REC2 + 128]; \
  i##B##5 = *(const float2*)(Lb + ((S)+5)*REC2 + 2*l); u##B##5 = Lb[((S)+5)*REC2 + 128]; \
  i##B##6 = *(const float2*)(Lb + ((S)+6)*REC2 + 2*l); u##B##6 = Lb[((S)+6)*REC2 + 128]; \
  i##B##7 = *(const float2*)(Lb + ((S)+7)*REC2 + 2*l); u##B##7 = Lb[((S)+7)*REC2 + 128];

#define KS8B(B, S)                                                            \
  KSTEP2(i##B##0, u##B##0, (S)+0)  KSTEP2(i##B##1, u##B##1, (S)+1)            \
  KSTEP2(i##B##2, u##B##2, (S)+2)  KSTEP2(i##B##3, u##B##3, (S)+3)            \
  KSTEP2(i##B##4, u##B##4, (S)+4)  KSTEP2(i##B##5, u##B##5, (S)+5)            \
  KSTEP2(i##B##6, u##B##6, (S)+6)  KSTEP2(i##B##7, u##B##7, (S)+7)

__global__ __launch_bounds__(256, 1) void k_smooth(float* __restrict__ ws) {
  __shared__ float buf[2][SCH*REC2];        // 2 x 34816 B
  const int n = blockIdx.x;
  const int tid = threadIdx.x;
  const int wave = tid >> 6, l = tid & 63;
  const float4* __restrict__ base4 =
      (const float4*)(ws + OFF_CI) + (size_t)n*(NWIN*REC2/4);

  // preload chunk 0 (all threads)
  {
    const float4* s4 = base4;
    float4* d4 = (float4*)&buf[0][0];
    for (int i = tid; i < CHF4; i += 256) d4[i] = s4[i];
  }
  __syncthreads();

  const float* c2p = ws + OFF_CMP2 + (size_t)n*REC2;
  const float Sv0   = c2p[2*l];
  const float Sv1   = c2p[2*l + 1];
  const float S128v = c2p[128];
  float qs = 0.f;
  float* qt = ws + OFF_QB + (size_t)n * 2048;
  if (wave == 0) __builtin_amdgcn_s_setprio(3);   // critical serial wave

  for (int c2 = 0; c2 < NCH; ++c2) {
    if (wave != 0) {
      if (c2 + 1 < NCH) {
        const float4* src = base4 + (size_t)(c2+1)*CHF4;
        float4* dst = (float4*)&buf[(c2+1) & 1][0];
        const int p = tid - 64;               // 0..191
        #pragma unroll
        for (int r = 0; r < 3; ++r) {
          int i0 = p + r*768;
          float4 a = src[i0];                 // loads unguarded (global pad)
          float4 b = src[i0 + 192];
          float4 cc = src[i0 + 384];
          float4 d = src[i0 + 576];
          if (i0       < CHF4) dst[i0]       = a;
          if (i0 + 192 < CHF4) dst[i0 + 192] = b;
          if (i0 + 384 < CHF4) dst[i0 + 384] = cc;
          if (i0 + 576 < CHF4) dst[i0 + 576] = d;
        }
      }
    } else {
      const float* Lb = &buf[c2 & 1][0];
      float qsave = 0.f;
      float2 iA0,iA1,iA2,iA3,iA4,iA5,iA6,iA7;
      float  uA0,uA1,uA2,uA3,uA4,uA5,uA6,uA7;
      float2 iB0,iB1,iB2,iB3,iB4,iB5,iB6,iB7;
      float  uB0,uB1,uB2,uB3,uB4,uB5,uB6,uB7;
      LD8B(A, 0)                               // steps 0..7
      for (int s = 0; s < SCH; s += 16) {
        LD8B(B, s+8)                           // steps s+8..s+15
        KS8B(A, s)                             // steps s..s+7
        if (s + 16 < SCH) { LD8B(A, s+16) }    // steps s+16..s+23
        KS8B(B, s+8)                           // steps s+8..s+15
      }
      qt[c2*SCH + l] = qsave;                  // lane l kept step l of chunk
    }
    __syncthreads();
  }
}

// tv = y * 10^((mk - p)/20): exact 128-step reconstruction from boundary q.
// lanes = tracks -> fully coalesced y/tv rows.
__global__ __launch_bounds__(256) void k_mix1(float* __restrict__ ws) {
  const int n  = threadIdx.x & 63;
  const int kk = blockIdx.x*4 + (threadIdx.x >> 6);
  const float* cm = ws + OFF_COMP + n*128;
  const float aa = cm[0], ar = cm[1], kca = cm[2], kcr = cm[3];
  const float T = cm[4], hK = cm[5], cg1 = cm[6], cg2 = cm[7];
  const float mkK = cm[8], sK = cm[9];
  const float* __restrict__ yb  = ws + OFF_Y;
  float* __restrict__       tvb = ws + OFF_TV;
  float q = (kk > 0) ? ws[OFF_QB + (size_t)n*2048 + (kk-1)] : 0.f;
  #pragma unroll 8
  for (int i = 0; i < SMW; ++i) {
    float y = yb[(size_t)(kk*SMW + i)*64 + n];
    float v   = fabsf(y) + 1e-8f;
    float xdb = 6.020599913279624f * __log2f(v);
    float d   = xdb - T;
    float dk  = d + hK;
    float gg  = (d > hK) ? (cg1*d) : (cg2*dk*dk);
    gg = (d < -hK) ? 0.f : gg;
    q = fmaxf(fmaf(aa, q, kca*gg), fmaf(ar, q, kcr*gg));
    float sc = exp2f(fmaf(-sK, q, mkK));
    tvb[(size_t)(kk*SMW + i)*64 + n] = y * sc;
  }
}

// 16-track pan reduction -> out[b][2][S]
__global__ __launch_bounds__(256) void k_mix2(const float* __restrict__ ws,
                                              float* __restrict__ out) {
  const int b = threadIdx.x & 3;
  const int s = blockIdx.x*64 + (threadIdx.x >> 2);
  const float* __restrict__ tvb = ws + OFF_TV;
  const float2* __restrict__ wp = (const float2*)(ws + OFF_W);
  float accL = 0.f, accR = 0.f;
  const int n0 = b*16;
  #pragma unroll
  for (int t = 0; t < 16; ++t) {
    float tv = tvb[(size_t)s*64 + n0 + t];
    float2 w2 = wp[n0 + t];
    accL = fmaf(w2.x, tv, accL);
    accR = fmaf(w2.y, tv, accR);
  }
  out[(size_t)(b*2 + 0)*S_LEN + s] = accL;
  out[(size_t)(b*2 + 1)*S_LEN + s] = accR;
}

// ---------------------------------------------------------------------------
extern "C" void kernel_launch(void* const* d_in, const int* in_sizes, int n_in,
                              void* d_out, int out_size, void* d_ws, size_t ws_size,
                              hipStream_t stream) {
  const float* tracks = (const float*)d_in[0];
  const float* mp     = (const float*)d_in[1];
  float* ws  = (float*)d_ws;
  float* out = (float*)d_out;

  hipLaunchKernelGGL(k_setup,   dim3(1),    dim3(64),  0, stream, mp, ws);
  hipLaunchKernelGGL(k_matpow,  dim3(64),   dim3(192), 0, stream, ws);
  hipLaunchKernelGGL(k_phase1,  dim3(CCH),  dim3(64),  0, stream, tracks, ws);
  hipLaunchKernelGGL(k_scanz_a, dim3(GRP),  dim3(256), 0, stream, ws);
  hipLaunchKernelGGL(k_scanz_b, dim3(4),    dim3(64),  0, stream, ws);
  hipLaunchKernelGGL(k_scanz_c, dim3(GRP),  dim3(256), 0, stream, ws);
  hipLaunchKernelGGL(k_phase3,  dim3(CCH),  dim3(64),  0, stream, tracks, ws);
  hipLaunchKernelGGL(k_smooth,  dim3(NTR),  dim3(256), 0, stream, ws);
  hipLaunchKernelGGL(k_mix1,    dim3(NWIN/4),  dim3(256), 0, stream, ws);
  hipLaunchKernelGGL(k_mix2,    dim3(S_LEN/64), dim3(256), 0, stream, ws, out);
}

// Round 17
// 326.595 us; speedup vs baseline: 1.8604x; 1.1506x over previous
//
#include <hip/hip_runtime.h>
#include <math.h>

// ---------------------------------------------------------------------------
// AdvancedMixConsole: 64 tracks x 131072 samples.
//   gain -> 6 biquads (chunk-parallel linear recurrence, 12-dim state)
//        -> compressor: parallel static gain; serial smoother over W=128
//           max-affine WINDOW MAPS built DIRECTLY in phase3
//        -> pan/mix (parallel, two-stage).
// R28: phase3 at WINDOW granularity (grid 1024, was 512 chunks): R27's
//      153us was spill-latency-bound at 2 blocks/CU (VGPR 144 vs ~180
//      live for I[129]; VALUBusy 36%). One window per block -> 4 blocks/CU
//      (4 SIMDs). Odd windows warm up the biquad state through the first
//      128 samples without map-build/y-writes (~10% redundant compute);
//      even blocks cover those y samples. Map build itself unchanged.
// ---------------------------------------------------------------------------

#define S_LEN 131072
#define NTR   64
#define CCH   512          // chunks (biquad phase)
#define LCH   256          // samples per chunk
#define GRP   32           // level-2 scan groups
#define GCH   16           // chunks per group
#define SMW   128          // smoother window
#define NWIN  1024         // windows per track
#define REC2  136          // floats per record (129 used)
#define SCH   64           // k_smooth steps per LDS chunk
#define NCH   16           // LDS chunks (1024/64)
#define CHF4  2176         // float4s per chunk (64*136/4)

typedef float v2f __attribute__((ext_vector_type(2)));

// ws offsets in floats (total ~73.3 MB)
#define OFF_Y    0ull              // [131072][64]      EQ output y, sample-major
#define OFF_CI   8388608ull        // [64][1024][136]   W=128 intercept records
#define OFF_TV   8388608ull        // [131072][64]      tv (ALIASES CI; used after k_smooth)
#define OFF_QB   17302528ull       // [64][2048]        boundary q per window (1024 used)
#define OFF_W    17433600ull       // [64][2]           cos/sin pan weights
#define OFF_COEF 17433728ull       // [64][32]          biquad coeffs
#define OFF_COMP 17435776ull       // [64][128]         compressor consts
#define OFF_A    17443968ull       // [64][144]         cascade transition matrix
#define OFF_M    17453184ull       // [64][144]         A^LCH
#define OFF_F    17462400ull       // [CCH][12][64]     zero-init chunk finals (track-minor)
#define OFF_Z    17855616ull       // [CCH][12][64]     chunk init states (track-minor)
#define OFF_GF   18248832ull       // [32][12][64]      group from-zero finals
#define OFF_GZ   18273408ull       // [32][12][64]      group initial states
#define OFF_M2   18297984ull       // [64][144]         (A^LCH)^16
#define OFF_CMP2 18307200ull       // [64][136]         129 W=128 slopes aa^j ar^(128-j)

// ---------------------------------------------------------------------------
__global__ __launch_bounds__(64) void k_setup(const float* __restrict__ mp,
                                              float* __restrict__ ws) {
  int n = threadIdx.x;
  if (n >= NTR) return;
  const float* p = mp + n * 26;
  auto dn = [&](int i, double lo, double hi) { return (double)p[i] * (hi - lo) + lo; };

  double gain_db = dn(0, -24.0, 24.0);
  double glin = pow(10.0, gain_db / 20.0);
  const double nyq = 21050.0;  // 44100//2 - 1000

  double fg[6] = {dn(1,-24,24), dn(4,-24,24), dn(7,-24,24), dn(10,-24,24), dn(13,-24,24), dn(16,-24,24)};
  double ff[6] = {dn(2,20,2000), dn(5,80,2000), dn(8,2000,8000), dn(11,8000,12000), dn(14,12000,nyq), dn(17,6000,nyq)};
  double fq[6] = {dn(3,0.1,5), dn(6,0.1,5), dn(9,0.1,5), dn(12,0.1,5), dn(15,0.1,5), dn(18,0.1,5)};

  double B0[6], B1[6], B2[6], A1[6], A2[6];
  for (int k = 0; k < 6; k++) {
    double A  = pow(10.0, fg[k] / 40.0);
    double w0 = 2.0 * M_PI * ff[k] / 44100.0;
    double cw = cos(w0), sw = sin(w0);
    double al = sw / (2.0 * fq[k]);
    double sA = sqrt(A);
    double b0, b1, b2, a0, a1, a2;
    if (k == 0) {           // low shelf
      b0 = A*((A+1)-(A-1)*cw + 2*sA*al);
      b1 = 2*A*((A-1)-(A+1)*cw);
      b2 = A*((A+1)-(A-1)*cw - 2*sA*al);
      a0 = (A+1)+(A-1)*cw + 2*sA*al;
      a1 = -2*((A-1)+(A+1)*cw);
      a2 = (A+1)+(A-1)*cw - 2*sA*al;
    } else if (k == 5) {    // high shelf
      b0 = A*((A+1)+(A-1)*cw + 2*sA*al);
      b1 = -2*A*((A-1)+(A+1)*cw);
      b2 = A*((A+1)+(A-1)*cw - 2*sA*al);
      a0 = (A+1)-(A-1)*cw + 2*sA*al;
      a1 = 2*((A-1)-(A+1)*cw);
      a2 = (A+1)-(A-1)*cw - 2*sA*al;
    } else {                // peak
      b0 = 1 + al*A; b1 = -2*cw; b2 = 1 - al*A;
      a0 = 1 + al/A; a1 = -2*cw; a2 = 1 - al/A;
    }
    B0[k] = b0/a0; B1[k] = b1/a0; B2[k] = b2/a0; A1[k] = a1/a0; A2[k] = a2/a0;
  }
  // fold input gain into stage-0 numerator
  B0[0] *= glin; B1[0] *= glin; B2[0] *= glin;

  float* cf = ws + OFF_COEF + n * 32;
  for (int k = 0; k < 6; k++) {
    cf[k*5+0] = (float)B0[k]; cf[k*5+1] = (float)B1[k]; cf[k*5+2] = (float)B2[k];
    cf[k*5+3] = (float)A1[k]; cf[k*5+4] = (float)A2[k];
  }

  // compressor + pan constants
  double T = dn(19,-60,0), R = dn(20,1,10), atk = dn(21,1,1000), rel = dn(22,1,1000);
  double Kn = dn(23,3,24), mk = dn(24,0,24);
  double a_a = exp(-1.0 / (44100.0 * atk * 0.001));
  double a_r = exp(-1.0 / (44100.0 * rel * 0.001));
  double s   = (a_a < a_r) ? 1.0 : -1.0;     // q = s*p makes the recurrence pure-max
  double kca = s * (1.0 - a_a), kcr = s * (1.0 - a_r);
  double invR = 1.0 / R;
  const double K10 = 0.16609640474436813;    // log2(10)/20
  double theta = (double)p[25] * (M_PI / 2.0);

  float* cm = ws + OFF_COMP + n * 128;
  cm[0] = (float)a_a;  cm[1] = (float)a_r;  cm[2] = (float)kca; cm[3] = (float)kcr;
  cm[4] = (float)T;    cm[5] = (float)(Kn * 0.5);
  cm[6] = (float)(1.0 - invR);
  cm[7] = (float)((1.0 - invR) / (2.0 * Kn));
  cm[8] = (float)(mk * K10);   cm[9] = (float)(s * K10);
  cm[10] = (float)cos(theta);  cm[11] = (float)sin(theta);
  // 129 W=128 slopes aa^j ar^(128-j) — incremental (2 pow + 128 fmul)
  {
    float* c2t = ws + OFF_CMP2 + (size_t)n*REC2;
    double sj = pow(a_r, 128.0);
    double ratio = a_a / a_r;
    for (int j = 0; j <= 128; j++) { c2t[j] = (float)sj; sj *= ratio; }
  }

  float* wp = ws + OFF_W + n*2;
  wp[0] = (float)cos(theta); wp[1] = (float)sin(theta);

  // homogeneous (x=0) cascade transition matrix, state = [s1_1,s2_1,...,s1_6,s2_6]
  double Am[12][12], yv[12], ny[12];
  for (int r = 0; r < 12; r++) { yv[r] = 0; for (int c = 0; c < 12; c++) Am[r][c] = 0; }
  for (int k = 0; k < 6; k++) {
    for (int c = 0; c < 12; c++) ny[c] = B0[k] * yv[c];
    ny[2*k] += 1.0;                                  // y_k = b0*y_{k-1} + s1_k
    for (int c = 0; c < 12; c++) Am[2*k][c]   = B1[k]*yv[c] - A1[k]*ny[c];
    Am[2*k][2*k+1] += 1.0;                           // + s2_k
    for (int c = 0; c < 12; c++) Am[2*k+1][c] = B2[k]*yv[c] - A2[k]*ny[c];
    for (int c = 0; c < 12; c++) yv[c] = ny[c];
  }
  float* Aw = ws + OFF_A + n * 144;
  for (int r = 0; r < 12; r++)
    for (int c = 0; c < 12; c++) Aw[r*12+c] = (float)Am[r][c];
}

// ---------------------------------------------------------------------------
// 12 squarings: store A^256 (=A^LCH) after 8, A^4096 (=(A^LCH)^16) after 12.
__global__ __launch_bounds__(192) void k_matpow(float* __restrict__ ws) {
  __shared__ float As[144];
  int n = blockIdx.x, t = threadIdx.x;
  int r = t / 12, c = t % 12;
  if (t < 144) As[t] = ws[OFF_A + (size_t)n*144 + t];
  __syncthreads();
  for (int it = 0; it < 12; ++it) {
    float acc = 0.f;
    if (t < 144) {
      #pragma unroll
      for (int k = 0; k < 12; k++) acc += As[r*12+k] * As[k*12+c];
    }
    __syncthreads();
    if (t < 144) As[t] = acc;
    __syncthreads();
    if (it == 7 && t < 144) ws[OFF_M + (size_t)n*144 + t] = As[t];   // A^256
  }
  if (t < 144) ws[OFF_M2 + (size_t)n*144 + t] = As[t];               // A^4096
}

// ---------------------------------------------------------------------------
__device__ __forceinline__ void load_coefs(const float* cf, float* b0, v2f* bb, v2f* naa) {
  #pragma unroll
  for (int k = 0; k < 6; k++) {
    b0[k]  = cf[k*5+0];
    bb[k]  = (v2f){cf[k*5+1], cf[k*5+2]};
    naa[k] = (v2f){-cf[k*5+3], -cf[k*5+4]};
  }
}

__device__ __forceinline__ float cascade_step(float x, float* b0, v2f* bb, v2f* naa, v2f* st) {
  #pragma unroll
  for (int k = 0; k < 6; k++) {
    float y  = fmaf(b0[k], x, st[k].x);
    v2f upd  = __builtin_elementwise_fma(bb[k], (v2f){x, x}, (v2f){st[k].y, 0.f});
    st[k]    = __builtin_elementwise_fma(naa[k], (v2f){y, y}, upd);
    x = y;
  }
  return x;
}

// phase 1: zero-init chunk finals
__global__ __launch_bounds__(64) void k_phase1(const float* __restrict__ tracks,
                                               float* __restrict__ ws) {
  int j = blockIdx.x, n = threadIdx.x;
  float b0[6]; v2f bb[6], naa[6];
  load_coefs(ws + OFF_COEF + n*32, b0, bb, naa);
  v2f st[6];
  #pragma unroll
  for (int k = 0; k < 6; k++) st[k] = (v2f){0.f, 0.f};
  const float4* xp = (const float4*)(tracks + (size_t)n*S_LEN + (size_t)j*LCH);
  for (int i4 = 0; i4 < LCH/4; ++i4) {
    float4 xq = xp[i4];
    float xs[4] = {xq.x, xq.y, xq.z, xq.w};
    #pragma unroll
    for (int u = 0; u < 4; u++) (void)cascade_step(xs[u], b0, bb, naa, st);
  }
  // track-minor layout [j][r][64]: 12 coalesced scalar stores
  float* f = ws + OFF_F + (size_t)j*(12*NTR) + n;
  #pragma unroll
  for (int k = 0; k < 6; k++) { f[(2*k)*64] = st[k].x; f[(2*k+1)*64] = st[k].y; }
}

// ---------------------------------------------------------------------------
// Blocked scan machinery (R21). Quad structure: 4 lanes per track instance.
__device__ __forceinline__ float qperm(float x, const int sel) {
  int xi = __float_as_int(x);
  int yi;
  switch (sel) {   // lane j receives from lane (j+k)&3 within its quad
    case 1:  yi = __builtin_amdgcn_update_dpp(xi, xi, 0x39, 0xf, 0xf, false); break; // [1,2,3,0]
    case 2:  yi = __builtin_amdgcn_update_dpp(xi, xi, 0x4E, 0xf, 0xf, false); break; // [2,3,0,1]
    default: yi = __builtin_amdgcn_update_dpp(xi, xi, 0x93, 0xf, 0xf, false); break; // [3,0,1,2]
  }
  return __int_as_float(yi);
}

// 36 named M scalars, columns in quad-rotation order (rows 3*sub..3*sub+2).
#define M_DECL(MBASE)                                                         \
  const int c0 = 3*((sub + 0) & 3), c1 = 3*((sub + 1) & 3),                   \
            c2 = 3*((sub + 2) & 3), c3 = 3*((sub + 3) & 3);                   \
  const float* Mb = (MBASE) + (3*sub)*12;                                     \
  float m0_0_0 = Mb[0*12+c0+0], m0_0_1 = Mb[1*12+c0+0], m0_0_2 = Mb[2*12+c0+0];\
  float m0_1_0 = Mb[0*12+c0+1], m0_1_1 = Mb[1*12+c0+1], m0_1_2 = Mb[2*12+c0+1];\
  float m0_2_0 = Mb[0*12+c0+2], m0_2_1 = Mb[1*12+c0+2], m0_2_2 = Mb[2*12+c0+2];\
  float m1_0_0 = Mb[0*12+c1+0], m1_0_1 = Mb[1*12+c1+0], m1_0_2 = Mb[2*12+c1+0];\
  float m1_1_0 = Mb[0*12+c1+1], m1_1_1 = Mb[1*12+c1+1], m1_1_2 = Mb[2*12+c1+1];\
  float m1_2_0 = Mb[0*12+c1+2], m1_2_1 = Mb[1*12+c1+2], m1_2_2 = Mb[2*12+c1+2];\
  float m2_0_0 = Mb[0*12+c2+0], m2_0_1 = Mb[1*12+c2+0], m2_0_2 = Mb[2*12+c2+0];\
  float m2_1_0 = Mb[0*12+c2+1], m2_1_1 = Mb[1*12+c2+1], m2_1_2 = Mb[2*12+c2+1];\
  float m2_2_0 = Mb[0*12+c2+2], m2_2_1 = Mb[1*12+c2+2], m2_2_2 = Mb[2*12+c2+2];\
  float m3_0_0 = Mb[0*12+c3+0], m3_0_1 = Mb[1*12+c3+0], m3_0_2 = Mb[2*12+c3+0];\
  float m3_1_0 = Mb[0*12+c3+1], m3_1_1 = Mb[1*12+c3+1], m3_1_2 = Mb[2*12+c3+1];\
  float m3_2_0 = Mb[0*12+c3+2], m3_2_1 = Mb[1*12+c3+2], m3_2_2 = Mb[2*12+c3+2];

// one scan step: z = M z + f, f at (FP)[0],[64],[128]
#define SCAN_STEP(FP)                                                         \
  {                                                                           \
    float t10 = qperm(z0,1), t11 = qperm(z1,1), t12 = qperm(z2,1);            \
    float t20 = qperm(z0,2), t21 = qperm(z1,2), t22 = qperm(z2,2);            \
    float t30 = qperm(z0,3), t31 = qperm(z1,3), t32 = qperm(z2,3);            \
    float a0 = (FP)[0], a1 = (FP)[64], a2 = (FP)[128];                        \
    a0 = fmaf(m0_0_0, z0, a0);  a1 = fmaf(m0_0_1, z0, a1);  a2 = fmaf(m0_0_2, z0, a2);  \
    a0 = fmaf(m0_1_0, z1, a0);  a1 = fmaf(m0_1_1, z1, a1);  a2 = fmaf(m0_1_2, z1, a2);  \
    a0 = fmaf(m0_2_0, z2, a0);  a1 = fmaf(m0_2_1, z2, a1);  a2 = fmaf(m0_2_2, z2, a2);  \
    a0 = fmaf(m1_0_0, t10, a0); a1 = fmaf(m1_0_1, t10, a1); a2 = fmaf(m1_0_2, t10, a2); \
    a0 = fmaf(m1_1_0, t11, a0); a1 = fmaf(m1_1_1, t11, a1); a2 = fmaf(m1_1_2, t11, a2); \
    a0 = fmaf(m1_2_0, t12, a0); a1 = fmaf(m1_2_1, t12, a1); a2 = fmaf(m1_2_2, t12, a2); \
    a0 = fmaf(m2_0_0, t20, a0); a1 = fmaf(m2_0_1, t20, a1); a2 = fmaf(m2_0_2, t20, a2); \
    a0 = fmaf(m2_1_0, t21, a0); a1 = fmaf(m2_1_1, t21, a1); a2 = fmaf(m2_1_2, t21, a2); \
    a0 = fmaf(m2_2_0, t22, a0); a1 = fmaf(m2_2_1, t22, a1); a2 = fmaf(m2_2_2, t22, a2); \
    a0 = fmaf(m3_0_0, t30, a0); a1 = fmaf(m3_0_1, t30, a1); a2 = fmaf(m3_0_2, t30, a2); \
    a0 = fmaf(m3_1_0, t31, a0); a1 = fmaf(m3_1_1, t31, a1); a2 = fmaf(m3_1_2, t31, a2); \
    a0 = fmaf(m3_2_0, t32, a0); a1 = fmaf(m3_2_1, t32, a1); a2 = fmaf(m3_2_2, t32, a2); \
    z0 = a0; z1 = a1; z2 = a2;                                                \
  }

// level-1: per-group from-zero finals (4-wave TLP hides reloads).
__global__ __launch_bounds__(256, 1) void k_scanz_a(float* __restrict__ ws) {
  const int tid = threadIdx.x;
  const int sub = tid & 3;
  const int n   = tid >> 2;          // track 0..63
  const int g   = blockIdx.x;        // group 0..31
  M_DECL(ws + OFF_M + (size_t)n*144)
  float z0 = 0.f, z1 = 0.f, z2 = 0.f;
  const float* __restrict__ fb = ws + OFF_F + (size_t)(g*GCH)*768 + (3*sub)*64 + n;
  #pragma unroll 4
  for (int k = 0; k < GCH; ++k) SCAN_STEP(fb + (size_t)k*768)
  float* gf = ws + OFF_GF + (size_t)g*768 + (3*sub)*64 + n;
  gf[0] = z0; gf[64] = z1; gf[128] = z2;
}

// level-2: serial scan over 32 group boundaries with M16=(A^LCH)^16.
__global__ __launch_bounds__(64, 1) void k_scanz_b(float* __restrict__ ws) {
  const int l   = threadIdx.x;
  const int sub = l & 3;
  const int n   = blockIdx.x*16 + (l >> 2);
  M_DECL(ws + OFF_M2 + (size_t)n*144)
  float z0 = 0.f, z1 = 0.f, z2 = 0.f;
  const float* __restrict__ fb = ws + OFF_GF + (3*sub)*64 + n;
  float*       __restrict__  zb = ws + OFF_GZ + (3*sub)*64 + n;
  for (int G = 0; G < GRP; ++G) {
    float* zp = zb + (size_t)G*768;
    zp[0] = z0; zp[64] = z1; zp[128] = z2;
    SCAN_STEP(fb + (size_t)G*768)
  }
}

// level-3: re-scan each group from its correct initial state.
__global__ __launch_bounds__(256, 1) void k_scanz_c(float* __restrict__ ws) {
  const int tid = threadIdx.x;
  const int sub = tid & 3;
  const int n   = tid >> 2;
  const int g   = blockIdx.x;
  M_DECL(ws + OFF_M + (size_t)n*144)
  const float* gz = ws + OFF_GZ + (size_t)g*768 + (3*sub)*64 + n;
  float z0 = gz[0], z1 = gz[64], z2 = gz[128];
  const float* __restrict__ fb = ws + OFF_F + (size_t)(g*GCH)*768 + (3*sub)*64 + n;
  float*       __restrict__  zb = ws + OFF_Z + (size_t)(g*GCH)*768 + (3*sub)*64 + n;
  #pragma unroll 4
  for (int k = 0; k < GCH; ++k) {
    float* zp = zb + (size_t)k*768;
    zp[0] = z0; zp[64] = z1; zp[128] = z2;
    SCAN_STEP(fb + (size_t)k*768)
  }
}

// ---------------------------------------------------------------------------
// phase 3: one WINDOW (128 samples) per block for 4-blocks/CU TLP.
// Odd windows warm up biquad state through samples 0..127 of the chunk
// (no map, no y-writes — even block covers those). Then direct W=128 map
// build: I[0..128] in registers, no validity guard (-1e30 decay trick),
// 8 segments x 16 samples with static jj-caps 16..128.
#define P3SEG(JJMAX)                                                          \
  for (int i4 = 0; i4 < 4; ++i4) {                                            \
    float4 xq = xp[w*32 + (soff >> 2) + i4];                                  \
    float xs[4] = {xq.x, xq.y, xq.z, xq.w};                                   \
    _Pragma("unroll")                                                         \
    for (int u = 0; u < 4; ++u) {                                             \
      float y = cascade_step(xs[u], b0, bb, naa, st);                         \
      yb[(w*128 + soff + i4*4 + u)*64] = y;                                   \
      float v   = fabsf(y) + 1e-8f;                                           \
      float xdb = 6.020599913279624f * __log2f(v);                            \
      float d   = xdb - T;                                                    \
      float dk  = d + hK;                                                     \
      float gg  = (d > hK) ? (cg1*d) : (cg2*dk*dk);                           \
      gg = (d < -hK) ? 0.f : gg;                                              \
      float ca = kca*gg, cr = kcr*gg;                                         \
      _Pragma("unroll")                                                       \
      for (int jj = (JJMAX); jj >= 1; --jj)                                   \
        I[jj] = fmaxf(fmaf(a_a, I[jj-1], ca), fmaf(a_r, I[jj], cr));          \
      I[0] = fmaf(a_r, I[0], cr);                                             \
    }                                                                         \
  }                                                                           \
  soff += 16;

__global__ __launch_bounds__(64, 1) void k_phase3(const float* __restrict__ tracks,
                                                  float* __restrict__ ws) {
  const int wg = blockIdx.x;        // global window 0..1023
  const int j  = wg >> 1;           // chunk
  const int w  = wg & 1;            // window within chunk
  const int n  = threadIdx.x;
  float b0[6]; v2f bb[6], naa[6];
  load_coefs(ws + OFF_COEF + n*32, b0, bb, naa);
  const float* cm = ws + OFF_COMP + n*128;
  float a_a = cm[0], a_r = cm[1], kca = cm[2], kcr = cm[3];
  float T = cm[4], hK = cm[5], cg1 = cm[6], cg2 = cm[7];
  v2f st[6];
  const float* zp = ws + OFF_Z + (size_t)j*(12*NTR) + n;   // track-minor: 12 coalesced loads
  #pragma unroll
  for (int k = 0; k < 6; k++) st[k] = (v2f){zp[(2*k)*64], zp[(2*k+1)*64]};

  const float4* xp = (const float4*)(tracks + (size_t)n*S_LEN + (size_t)j*LCH);
  float* yb = ws + OFF_Y + (size_t)j*LCH*64 + n;                        // [sample][track]

  if (w == 1) {
    // warm up state through samples 0..127 (even block writes their y)
    for (int i4 = 0; i4 < 32; ++i4) {
      float4 xq = xp[i4];
      float xs[4] = {xq.x, xq.y, xq.z, xq.w};
      #pragma unroll
      for (int u = 0; u < 4; ++u) (void)cascade_step(xs[u], b0, bb, naa, st);
    }
  }

  float I[129];
  I[0] = 0.f;
  #pragma unroll
  for (int jj = 1; jj < 129; ++jj) I[jj] = -1e30f;
  int soff = 0;
  P3SEG(16)  P3SEG(32)  P3SEG(48)  P3SEG(64)
  P3SEG(80)  P3SEG(96)  P3SEG(112) P3SEG(128)

  float* cw = ws + OFF_CI + (size_t)n*(NWIN*REC2) + (size_t)wg*REC2;
  float4* cq = (float4*)cw;
  #pragma unroll
  for (int r = 0; r < 32; ++r)
    cq[r] = make_float4(I[4*r], I[4*r+1], I[4*r+2], I[4*r+3]);
  cw[128] = I[128];
}

// ---------------------------------------------------------------------------
// serial max-affine smoother over W=128 maps. 1024 steps/track.
// Lane l owns slopes 2l,2l+1 (regs) + uniform term 128. Per step:
// ds_read_b64 + uniform read, 3 fma, max3, 6-stage fused DPP reduce,
// readlane -> SGPR q. 8-step A/B banks amortize lgkmcnt. Producer waves
// 1-3 double-buffer 64-record (34.8KB) chunks.
#define KSTEP2(IV, UV, SS)                                                    \
  {                                                                           \
    float f0  = fmaf(Sv0, qs, (IV).x);                                        \
    float f1  = fmaf(Sv1, qs, (IV).y);                                        \
    float fu  = fmaf(S128v, qs, (UV));                                        \
    float t   = fmaxf(fmaxf(f0, f1), fu);                                     \
    asm("s_nop 1\n\t"                                                         \
        "v_max_f32_dpp %0, %0, %0 row_shr:1 row_mask:0xf bank_mask:0xf\n\t"   \
        "s_nop 1\n\t"                                                         \
        "v_max_f32_dpp %0, %0, %0 row_shr:2 row_mask:0xf bank_mask:0xf\n\t"   \
        "s_nop 1\n\t"                                                         \
        "v_max_f32_dpp %0, %0, %0 row_shr:4 row_mask:0xf bank_mask:0xf\n\t"   \
        "s_nop 1\n\t"                                                         \
        "v_max_f32_dpp %0, %0, %0 row_shr:8 row_mask:0xf bank_mask:0xf\n\t"   \
        "s_nop 1\n\t"                                                         \
        "v_max_f32_dpp %0, %0, %0 row_bcast:15 row_mask:0xa bank_mask:0xf\n\t"\
        "s_nop 1\n\t"                                                         \
        "v_max_f32_dpp %0, %0, %0 row_bcast:31 row_mask:0xc bank_mask:0xf\n\t"\
        "s_nop 1"                                                             \
        : "+v"(t));                                                           \
    qs = __int_as_float(__builtin_amdgcn_readlane(__float_as_int(t), 63));    \
    qsave = ((SS) == l) ? qs : qsave;                                         \
  }

#define LD8B(B, S)                                                            \
  i##B##0 = *(const float2*)(Lb + ((S)+0)*REC2 + 2*l); u##B##0 = Lb[((S)+0)*REC2 + 128]; \
  i##B##1 = *(const float2*)(Lb + ((S)+1)*REC2 + 2*l); u##B##1 = Lb[((S)+1)*REC2 + 128]; \
  i##B##2 = *(const float2*)(Lb + ((S)+2)*REC2 + 2*l); u##B##2 = Lb[((S)+2)*REC2 + 128]; \
  i##B##3 = *(const float2*)(Lb + ((S)+3)*REC2 + 2*l); u##B##3 = Lb[((S)+3)*REC2 + 128]; \
  i##B##4 = *(const float2*)(Lb + ((S)+4)*REC2 + 2*l); u##B##4 = Lb[((S)+4)*REC2 + 128]; \
  i##B##5 = *(const float2*)(Lb + ((S)+5)*REC2 + 2*l); u##B##5 = Lb[((S)+5)*REC2 + 128]; \
  i##B##6 = *(const float2*)(Lb + ((S)+6)*REC2 + 2*l); u##B##6 = Lb[((S)+6)*REC2 + 128]; \
  i##B##7 = *(const float2*)(Lb + ((S)+7)*REC2 + 2*l); u##B##7 = Lb[((S)+7)*REC2 + 128];

#define KS8B(B, S)                                                            \
  KSTEP2(i##B##0, u##B##0, (S)+0)  KSTEP2(i##B##1, u##B##1, (S)+1)            \
  KSTEP2(i##B##2, u##B##2, (S)+2)  KSTEP2(i##B##3, u##B##3, (S)+3)            \
  KSTEP2(i##B##4, u##B##4, (S)+4)  KSTEP2(i##B##5, u##B##5, (S)+5)            \
  KSTEP2(i##B##6, u##B##6, (S)+6)  KSTEP2(i##B##7, u##B##7, (S)+7)

__global__ __launch_bounds__(256, 1) void k_smooth(float* __restrict__ ws) {
  __shared__ float buf[2][SCH*REC2];        // 2 x 34816 B
  const int n = blockIdx.x;
  const int tid = threadIdx.x;
  const int wave = tid >> 6, l = tid & 63;
  const float4* __restrict__ base4 =
      (const float4*)(ws + OFF_CI) + (size_t)n*(NWIN*REC2/4);

  // preload chunk 0 (all threads)
  {
    const float4* s4 = base4;
    float4* d4 = (float4*)&buf[0][0];
    for (int i = tid; i < CHF4; i += 256) d4[i] = s4[i];
  }
  __syncthreads();

  const float* c2p = ws + OFF_CMP2 + (size_t)n*REC2;
  const float Sv0   = c2p[2*l];
  const float Sv1   = c2p[2*l + 1];
  const float S128v = c2p[128];
  float qs = 0.f;
  float* qt = ws + OFF_QB + (size_t)n * 2048;
  if (wave == 0) __builtin_amdgcn_s_setprio(3);   // critical serial wave

  for (int c2 = 0; c2 < NCH; ++c2) {
    if (wave != 0) {
      if (c2 + 1 < NCH) {
        const float4* src = base4 + (size_t)(c2+1)*CHF4;
        float4* dst = (float4*)&buf[(c2+1) & 1][0];
        const int p = tid - 64;               // 0..191
        #pragma unroll
        for (int r = 0; r < 3; ++r) {
          int i0 = p + r*768;
          float4 a = src[i0];                 // loads unguarded (global pad)
          float4 b = src[i0 + 192];
          float4 cc = src[i0 + 384];
          float4 d = src[i0 + 576];
          if (i0       < CHF4) dst[i0]       = a;
          if (i0 + 192 < CHF4) dst[i0 + 192] = b;
          if (i0 + 384 < CHF4) dst[i0 + 384] = cc;
          if (i0 + 576 < CHF4) dst[i0 + 576] = d;
        }
      }
    } else {
      const float* Lb = &buf[c2 & 1][0];
      float qsave = 0.f;
      float2 iA0,iA1,iA2,iA3,iA4,iA5,iA6,iA7;
      float  uA0,uA1,uA2,uA3,uA4,uA5,uA6,uA7;
      float2 iB0,iB1,iB2,iB3,iB4,iB5,iB6,iB7;
      float  uB0,uB1,uB2,uB3,uB4,uB5,uB6,uB7;
      LD8B(A, 0)                               // steps 0..7
      for (int s = 0; s < SCH; s += 16) {
        LD8B(B, s+8)                           // steps s+8..s+15
        KS8B(A, s)                             // steps s..s+7
        if (s + 16 < SCH) { LD8B(A, s+16) }    // steps s+16..s+23
        KS8B(B, s+8)                           // steps s+8..s+15
      }
      qt[c2*SCH + l] = qsave;                  // lane l kept step l of chunk
    }
    __syncthreads();
  }
}

// tv = y * 10^((mk - p)/20): exact 128-step reconstruction from boundary q.
// lanes = tracks -> fully coalesced y/tv rows.
__global__ __launch_bounds__(256) void k_mix1(float* __restrict__ ws) {
  const int n  = threadIdx.x & 63;
  const int kk = blockIdx.x*4 + (threadIdx.x >> 6);
  const float* cm = ws + OFF_COMP + n*128;
  const float aa = cm[0], ar = cm[1], kca = cm[2], kcr = cm[3];
  const float T = cm[4], hK = cm[5], cg1 = cm[6], cg2 = cm[7];
  const float mkK = cm[8], sK = cm[9];
  const float* __restrict__ yb  = ws + OFF_Y;
  float* __restrict__       tvb = ws + OFF_TV;
  float q = (kk > 0) ? ws[OFF_QB + (size_t)n*2048 + (kk-1)] : 0.f;
  #pragma unroll 8
  for (int i = 0; i < SMW; ++i) {
    float y = yb[(size_t)(kk*SMW + i)*64 + n];
    float v   = fabsf(y) + 1e-8f;
    float xdb = 6.020599913279624f * __log2f(v);
    float d   = xdb - T;
    float dk  = d + hK;
    float gg  = (d > hK) ? (cg1*d) : (cg2*dk*dk);
    gg = (d < -hK) ? 0.f : gg;
    q = fmaxf(fmaf(aa, q, kca*gg), fmaf(ar, q, kcr*gg));
    float sc = exp2f(fmaf(-sK, q, mkK));
    tvb[(size_t)(kk*SMW + i)*64 + n] = y * sc;
  }
}

// 16-track pan reduction -> out[b][2][S]
__global__ __launch_bounds__(256) void k_mix2(const float* __restrict__ ws,
                                              float* __restrict__ out) {
  const int b = threadIdx.x & 3;
  const int s = blockIdx.x*64 + (threadIdx.x >> 2);
  const float* __restrict__ tvb = ws + OFF_TV;
  const float2* __restrict__ wp = (const float2*)(ws + OFF_W);
  float accL = 0.f, accR = 0.f;
  const int n0 = b*16;
  #pragma unroll
  for (int t = 0; t < 16; ++t) {
    float tv = tvb[(size_t)s*64 + n0 + t];
    float2 w2 = wp[n0 + t];
    accL = fmaf(w2.x, tv, accL);
    accR = fmaf(w2.y, tv, accR);
  }
  out[(size_t)(b*2 + 0)*S_LEN + s] = accL;
  out[(size_t)(b*2 + 1)*S_LEN + s] = accR;
}

// ---------------------------------------------------------------------------
extern "C" void kernel_launch(void* const* d_in, const int* in_sizes, int n_in,
                              void* d_out, int out_size, void* d_ws, size_t ws_size,
                              hipStream_t stream) {
  const float* tracks = (const float*)d_in[0];
  const float* mp     = (const float*)d_in[1];
  float* ws  = (float*)d_ws;
  float* out = (float*)d_out;

  hipLaunchKernelGGL(k_setup,   dim3(1),    dim3(64),  0, stream, mp, ws);
  hipLaunchKernelGGL(k_matpow,  dim3(64),   dim3(192), 0, stream, ws);
  hipLaunchKernelGGL(k_phase1,  dim3(CCH),  dim3(64),  0, stream, tracks, ws);
  hipLaunchKernelGGL(k_scanz_a, dim3(GRP),  dim3(256), 0, stream, ws);
  hipLaunchKernelGGL(k_scanz_b, dim3(4),    dim3(64),  0, stream, ws);
  hipLaunchKernelGGL(k_scanz_c, dim3(GRP),  dim3(256), 0, stream, ws);
  hipLaunchKernelGGL(k_phase3,  dim3(NWIN), dim3(64),  0, stream, tracks, ws);
  hipLaunchKernelGGL(k_smooth,  dim3(NTR),  dim3(256), 0, stream, ws);
  hipLaunchKernelGGL(k_mix1,    dim3(NWIN/4),  dim3(256), 0, stream, ws);
  hipLaunchKernelGGL(k_mix2,    dim3(S_LEN/64), dim3(256), 0, stream, ws, out);
}